// Round 32
// baseline (143.335 us; speedup 1.0000x reference)
//
#include <hip/hip_runtime.h>
#include <hip/hip_bf16.h>

// MultiHeadAttention fused pipeline, MI355X gfx950.
// B=8, S=1024 (N=1023 + 1 global), HID=512, H=8, D=64.
// Stages: qkv_trans (merged qkv_proj + ab_transpose grid) -> qh/kh/vht2 + abT u8;
//         attn_fused (LDS-staged, dbuf, b-keyed XCD clustering) -> partials;
//         out_proj fuses partial-combine + normalize -> f32 out.
// Ladder: 194 -> 148 -> 128.2 -> 127.8 -> 125.9 -> 124.6 -> 121.3 (u8 abT).
// R32: MERGE qkv + ab_transpose into one 2816-block grid. Rationale: qkv is
//   latency-bound (20% HBM, 9% MFMA, 24% VALU, ~2.2 blocks/CU) with a 14us BW
//   floor; transpose is a pure 3TB/s stream. Co-residency lets transpose
//   traffic fill qkv's latency bubbles (blocks 0..767 qkv, 768.. transpose;
//   uniform branch; transpose LDS tile ALIASES lda[2] so LDS stays 40960).
//   Both paths byte-identical to R31. Gate: merged >= 60us => revert.

typedef __attribute__((ext_vector_type(8)))  __bf16 bf16x8;
typedef __attribute__((ext_vector_type(16))) float  f32x16;

__device__ inline f32x16 zero16(){
  f32x16 z;
  #pragma unroll
  for (int i=0;i<16;i++) z[i] = 0.0f;
  return z;
}

__device__ inline unsigned short f2bf(float x){           // RNE f32->bf16
  unsigned u = __float_as_uint(x);
  u += 0x7fffu + ((u>>16)&1u);
  return (unsigned short)(u>>16);
}
__device__ inline unsigned f2bf_pair(float a, float b){   // pack 2 bf16 into dword (RNE)
  unsigned ua = __float_as_uint(a); ua += 0x7fffu + ((ua>>16)&1u);
  unsigned ub = __float_as_uint(b); ub += 0x7fffu + ((ub>>16)&1u);
  return (ua>>16) | (ub & 0xffff0000u);
}
// combine two packed-bf16 dwords: (a+b)*rn per element, repacked bf16
__device__ inline unsigned comb2(unsigned a, unsigned b, float rn){
  const float a0 = __uint_as_float(a<<16), a1 = __uint_as_float(a & 0xffff0000u);
  const float b0 = __uint_as_float(b<<16), b1 = __uint_as_float(b & 0xffff0000u);
  return f2bf_pair((a0+b0)*rn, (a1+b1)*rn);
}

__device__ inline void bar_lgkm(){   // LDS-visibility barrier WITHOUT vmcnt drain
  asm volatile("s_waitcnt lgkmcnt(0)" ::: "memory");
  __builtin_amdgcn_s_barrier();
}

// ---------------------------------------------------------------------------
// MERGED: qkv projection (blocks 0..767) + ab transpose (blocks 768..2815).
// qkv path: 128x128 tile, dbuf 1-barrier, 16 MFMA/K-step (R26/R28 proven).
//   sel=0: qh = (q Wq^T + bq)*scaleq; sel=1: kh; sel=2 (swapped): vht2 blocked.
// transpose path: abT[b][t][q] = (q<1023 && t<1023) ? (u8)ab[b][q][t] : 255;
//   64x64 tile via LDS (65-pad), tile ALIASED onto lda (16640B < 20480B).
// ---------------------------------------------------------------------------
__global__ __launch_bounds__(256)
void qkv_trans(const float* xq, const float* xk, const float* xv,
               const float* Wq, const float* Wk, const float* Wv,
               const float* bq, const float* bk, const float* bv,
               const int* ab,
               unsigned short* qh, unsigned short* kh, unsigned short* vht2,
               unsigned char* abT, float scaleq)
{
  __shared__ unsigned short lda[2][128*40];   // 40-pad rows (20480 B)
  __shared__ unsigned short ldb[2][128*40];
  const int bid = blockIdx.x;

  if (bid >= 768){
    // ---------------- ab transpose path (aliases lda as int tile) ----------
    int* tl = (int*)&lda[0][0];              // 64*65*4 = 16640 B
    const int k  = bid - 768;
    const int b  = k >> 8;
    const int ti = k & 255;
    const int t0 = (ti & 15) << 6, q0 = (ti >> 4) << 6;
    const int c  = threadIdx.x & 63, r0 = threadIdx.x >> 6;
    #pragma unroll
    for (int rp = 0; rp < 16; ++rp){
      const int r = r0 + rp*4;
      const int q = q0 + r, t = t0 + c;
      int v = 255;
      if (q < 1023 && t < 1023) v = ab[((size_t)b*1023 + q)*1023 + t];
      tl[r*65 + c] = v;
    }
    __syncthreads();
    unsigned char* dst = abT + ((size_t)b << 20);
    #pragma unroll
    for (int rp = 0; rp < 16; ++rp){
      const int r = r0 + rp*4;               // r = t offset, c = q offset
      dst[(size_t)(t0 + r)*1024 + q0 + c] = (unsigned char)tl[c*65 + r];
    }
    return;
  }

  // ---------------- qkv projection path (byte-identical to R31) -----------
  const int sel = bid >> 8;                // uniform per block
  const int t   = bid & 255;
  const float *RA, *RB, *bias;
  int r0, c0;
  if (sel == 0){ RA = xq; RB = Wq; bias = bq; r0 = (t&63)*128; c0 = (t>>6)*128; }
  else if (sel == 1){ RA = xk; RB = Wk; bias = bk; r0 = (t&63)*128; c0 = (t>>6)*128; }
  else { RA = Wv; RB = xv; bias = bv; r0 = (t&3)*128; c0 = (t>>2)*128; }

  const int tid  = threadIdx.x;
  const int w    = tid>>6, lane = tid&63, lo = lane&31, hi = lane>>5;
  const int wr   = (w>>1)*64, wc = (w&1)*64;
  const int arow = tid>>1, kb = (tid&1)*16;

  f32x16 acc[2][2];
  #pragma unroll
  for (int i=0;i<2;i++)
    #pragma unroll
    for (int j=0;j<2;j++) acc[i][j] = zero16();

  float4 ra[4], rb4[4];

  // ---- prologue: load tile0; stage into buf0; load tile1; barrier ----
  {
    const float4* p = (const float4*)(RA + (r0+arow)*512 + kb);
    ra[0]=p[0]; ra[1]=p[1]; ra[2]=p[2]; ra[3]=p[3];
    const float4* pq = (const float4*)(RB + (c0+arow)*512 + kb);
    rb4[0]=pq[0]; rb4[1]=pq[1]; rb4[2]=pq[2]; rb4[3]=pq[3];
  }
  {
    uint4 w0, w1;
    w0.x = f2bf_pair(ra[0].x, ra[0].y); w0.y = f2bf_pair(ra[0].z, ra[0].w);
    w0.z = f2bf_pair(ra[1].x, ra[1].y); w0.w = f2bf_pair(ra[1].z, ra[1].w);
    w1.x = f2bf_pair(ra[2].x, ra[2].y); w1.y = f2bf_pair(ra[2].z, ra[2].w);
    w1.z = f2bf_pair(ra[3].x, ra[3].y); w1.w = f2bf_pair(ra[3].z, ra[3].w);
    uint4* pa = (uint4*)&lda[0][arow*40 + kb];
    pa[0] = w0; pa[1] = w1;
    uint4 v0, v1;
    v0.x = f2bf_pair(rb4[0].x, rb4[0].y); v0.y = f2bf_pair(rb4[0].z, rb4[0].w);
    v0.z = f2bf_pair(rb4[1].x, rb4[1].y); v0.w = f2bf_pair(rb4[1].z, rb4[1].w);
    v1.x = f2bf_pair(rb4[2].x, rb4[2].y); v1.y = f2bf_pair(rb4[2].z, rb4[2].w);
    v1.z = f2bf_pair(rb4[3].x, rb4[3].y); v1.w = f2bf_pair(rb4[3].z, rb4[3].w);
    uint4* pb = (uint4*)&ldb[0][arow*40 + kb];
    pb[0] = v0; pb[1] = v1;
  }
  {
    const float4* p = (const float4*)(RA + (r0+arow)*512 + 32 + kb);
    ra[0]=p[0]; ra[1]=p[1]; ra[2]=p[2]; ra[3]=p[3];
    const float4* pq = (const float4*)(RB + (c0+arow)*512 + 32 + kb);
    rb4[0]=pq[0]; rb4[1]=pq[1]; rb4[2]=pq[2]; rb4[3]=pq[3];
  }
  bar_lgkm();   // buf0 visible

  for (int ks=0; ks<16; ++ks){
    const int cur = ks & 1;
    // stage tile ks+1 into the OTHER buffer (regs loaded last iter)
    if (ks < 15){
      uint4 w0, w1;
      w0.x = f2bf_pair(ra[0].x, ra[0].y); w0.y = f2bf_pair(ra[0].z, ra[0].w);
      w0.z = f2bf_pair(ra[1].x, ra[1].y); w0.w = f2bf_pair(ra[1].z, ra[1].w);
      w1.x = f2bf_pair(ra[2].x, ra[2].y); w1.y = f2bf_pair(ra[2].z, ra[2].w);
      w1.z = f2bf_pair(ra[3].x, ra[3].y); w1.w = f2bf_pair(ra[3].z, ra[3].w);
      uint4* pa = (uint4*)&lda[cur^1][arow*40 + kb];
      pa[0] = w0; pa[1] = w1;
      uint4 v0, v1;
      v0.x = f2bf_pair(rb4[0].x, rb4[0].y); v0.y = f2bf_pair(rb4[0].z, rb4[0].w);
      v0.z = f2bf_pair(rb4[1].x, rb4[1].y); v0.w = f2bf_pair(rb4[1].z, rb4[1].w);
      v1.x = f2bf_pair(rb4[2].x, rb4[2].y); v1.y = f2bf_pair(rb4[2].z, rb4[2].w);
      v1.z = f2bf_pair(rb4[3].x, rb4[3].y); v1.w = f2bf_pair(rb4[3].z, rb4[3].w);
      uint4* pb = (uint4*)&ldb[cur^1][arow*40 + kb];
      pb[0] = v0; pb[1] = v1;
    }
    // issue loads for tile ks+2 (in flight across the barrier)
    if (ks < 14){
      const int k0 = (ks+2)*32;
      const float4* p = (const float4*)(RA + (r0+arow)*512 + k0 + kb);
      ra[0]=p[0]; ra[1]=p[1]; ra[2]=p[2]; ra[3]=p[3];
      const float4* pq = (const float4*)(RB + (c0+arow)*512 + k0 + kb);
      rb4[0]=pq[0]; rb4[1]=pq[1]; rb4[2]=pq[2]; rb4[3]=pq[3];
    }
    // MFMA from current buffer (visible via previous barrier)
    #pragma unroll
    for (int kf=0; kf<2; ++kf){
      bf16x8 af0 = *(const bf16x8*)&lda[cur][(wr+lo)*40    + kf*16 + hi*8];
      bf16x8 af1 = *(const bf16x8*)&lda[cur][(wr+32+lo)*40 + kf*16 + hi*8];
      bf16x8 bg0 = *(const bf16x8*)&ldb[cur][(wc+lo)*40    + kf*16 + hi*8];
      bf16x8 bg1 = *(const bf16x8*)&ldb[cur][(wc+32+lo)*40 + kf*16 + hi*8];
      acc[0][0] = __builtin_amdgcn_mfma_f32_32x32x16_bf16(af0, bg0, acc[0][0], 0,0,0);
      acc[0][1] = __builtin_amdgcn_mfma_f32_32x32x16_bf16(af0, bg1, acc[0][1], 0,0,0);
      acc[1][0] = __builtin_amdgcn_mfma_f32_32x32x16_bf16(af1, bg0, acc[1][0], 0,0,0);
      acc[1][1] = __builtin_amdgcn_mfma_f32_32x32x16_bf16(af1, bg1, acc[1][1], 0,0,0);
    }
    // ONE barrier: my reads of buf[cur] + writes of buf[cur^1] all drained
    bar_lgkm();
  }

  // epilogue; C/D layout: col = lane&31, row = (r&3)+8*(r>>2)+4*(lane>>5)
  #pragma unroll
  for (int mi=0;mi<2;mi++){
    #pragma unroll
    for (int ni=0;ni<2;ni++){
      #pragma unroll
      for (int r=0;r<16;r++){
        const int rl = wr + mi*32 + (r&3) + 8*(r>>2) + 4*hi;
        const int cl = wc + ni*32 + lo;
        const int rg = r0 + rl, cg = c0 + cl;
        float v = acc[mi][ni][r];
        if (sel == 0){
          v = (v + bias[cg]) * scaleq;
          const int bb = rg>>10, s = rg&1023, h = cg>>6, d = cg&63;
          qh[(((bb*8+h)*1024)+s)*64 + d] = f2bf(v);
        } else if (sel == 1){
          v = v + bias[cg];
          const int bb = rg>>10, s = rg&1023, h = cg>>6, d = cg&63;
          kh[(((bb*8+h)*1024)+s)*64 + d] = f2bf(v);
        } else {
          v = v + bias[rg];
          const int h = rg>>6, d = rg&63, bb = cg>>10, s = cg&1023;
          vht2[(((size_t)(bb*8+h)*32 + (s>>5))*64 + d)*32 + (s&31)] = f2bf(v);
        }
      }
    }
  }
}

// ---------------------------------------------------------------------------
// Out projection with fused partial-combine:
//   A[row][k] = (ctx0[row][k] + ctx1[row][k]) / (l0[b,h,s] + l1[b,h,s])
//   out[8192][512] = A Wo^T + bo (f32).
// ---------------------------------------------------------------------------
__global__ __launch_bounds__(256)
void out_proj(const unsigned short* ctx0, const unsigned short* ctx1,
              const float* lsump, const float* Wo, const float* bo, float* OUT)
{
  __shared__ unsigned short lda[128*40];
  __shared__ unsigned short ldb[128*40];
  const int tid  = threadIdx.x;
  const int r0   = blockIdx.x*128, c0 = blockIdx.y*128;
  const int w    = tid>>6, lane = tid&63, lo = lane&31, hi = lane>>5;
  const int wr   = (w>>1)*64, wc = (w&1)*64;
  const int arow = tid>>1, kb = (tid&1)*16;
  const int rgs  = r0 + arow, bb = rgs>>10, ss = rgs&1023;
  const float* lb0 = lsump + (size_t)(bb*8)*1024 + ss;        // ts=0, + h*1024
  const float* lb1 = lsump + (size_t)((8+bb)*8)*1024 + ss;    // ts=1

  f32x16 acc[2][2];
  #pragma unroll
  for (int i=0;i<2;i++)
    #pragma unroll
    for (int j=0;j<2;j++) acc[i][j] = zero16();

  uint4 ra0[2], ra1[2];
  float4 rb4[4];
  float l0, l1;

  {
    const uint4* p0 = (const uint4*)(ctx0 + rgs*512 + kb);
    ra0[0]=p0[0]; ra0[1]=p0[1];
    const uint4* p1 = (const uint4*)(ctx1 + rgs*512 + kb);
    ra1[0]=p1[0]; ra1[1]=p1[1];
    const int h = kb>>6;
    l0 = lb0[h*1024]; l1 = lb1[h*1024];
    const float4* pq = (const float4*)(Wo + (c0+arow)*512 + kb);
    rb4[0]=pq[0]; rb4[1]=pq[1]; rb4[2]=pq[2]; rb4[3]=pq[3];
  }

  for (int ks=0; ks<16; ++ks){
    bar_lgkm();
    {
      const float rn = __builtin_amdgcn_rcpf(l0 + l1);
      uint4 w0, w1;
      w0.x = comb2(ra0[0].x, ra1[0].x, rn); w0.y = comb2(ra0[0].y, ra1[0].y, rn);
      w0.z = comb2(ra0[0].z, ra1[0].z, rn); w0.w = comb2(ra0[0].w, ra1[0].w, rn);
      w1.x = comb2(ra0[1].x, ra1[1].x, rn); w1.y = comb2(ra0[1].y, ra1[1].y, rn);
      w1.z = comb2(ra0[1].z, ra1[1].z, rn); w1.w = comb2(ra0[1].w, ra1[1].w, rn);
      uint4* pa = (uint4*)&lda[arow*40 + kb];
      pa[0] = w0; pa[1] = w1;
      uint4 v0, v1;
      v0.x = f2bf_pair(rb4[0].x, rb4[0].y); v0.y = f2bf_pair(rb4[0].z, rb4[0].w);
      v0.z = f2bf_pair(rb4[1].x, rb4[1].y); v0.w = f2bf_pair(rb4[1].z, rb4[1].w);
      v1.x = f2bf_pair(rb4[2].x, rb4[2].y); v1.y = f2bf_pair(rb4[2].z, rb4[2].w);
      v1.z = f2bf_pair(rb4[3].x, rb4[3].y); v1.w = f2bf_pair(rb4[3].z, rb4[3].w);
      uint4* pb = (uint4*)&ldb[arow*40 + kb];
      pb[0] = v0; pb[1] = v1;
    }
    if (ks < 15){
      const int k0 = (ks+1)*32;
      const uint4* p0 = (const uint4*)(ctx0 + rgs*512 + k0 + kb);
      ra0[0]=p0[0]; ra0[1]=p0[1];
      const uint4* p1 = (const uint4*)(ctx1 + rgs*512 + k0 + kb);
      ra1[0]=p1[0]; ra1[1]=p1[1];
      const int h = (k0+kb)>>6;
      l0 = lb0[h*1024]; l1 = lb1[h*1024];
      const float4* pq = (const float4*)(Wo + (c0+arow)*512 + k0 + kb);
      rb4[0]=pq[0]; rb4[1]=pq[1]; rb4[2]=pq[2]; rb4[3]=pq[3];
    }
    bar_lgkm();
    #pragma unroll
    for (int kf=0; kf<2; ++kf){
      bf16x8 af0 = *(const bf16x8*)&lda[(wr+lo)*40    + kf*16 + hi*8];
      bf16x8 af1 = *(const bf16x8*)&lda[(wr+32+lo)*40 + kf*16 + hi*8];
      bf16x8 bg0 = *(const bf16x8*)&ldb[(wc+lo)*40    + kf*16 + hi*8];
      bf16x8 bg1 = *(const bf16x8*)&ldb[(wc+32+lo)*40 + kf*16 + hi*8];
      acc[0][0] = __builtin_amdgcn_mfma_f32_32x32x16_bf16(af0, bg0, acc[0][0], 0,0,0);
      acc[0][1] = __builtin_amdgcn_mfma_f32_32x32x16_bf16(af0, bg1, acc[0][1], 0,0,0);
      acc[1][0] = __builtin_amdgcn_mfma_f32_32x32x16_bf16(af1, bg0, acc[1][0], 0,0,0);
      acc[1][1] = __builtin_amdgcn_mfma_f32_32x32x16_bf16(af1, bg1, acc[1][1], 0,0,0);
    }
  }

  #pragma unroll
  for (int mi=0;mi<2;mi++){
    #pragma unroll
    for (int ni=0;ni<2;ni++){
      #pragma unroll
      for (int r=0;r<16;r++){
        const int rl = wr + mi*32 + (r&3) + 8*(r>>2) + 4*hi;
        const int cl = wc + ni*32 + lo;
        const int rg = r0 + rl, cg = c0 + cl;
        OUT[rg*512 + cg] = acc[mi][ni][r] + bo[cg];
      }
    }
  }
}

// ---------------------------------------------------------------------------
// Fused attention, LDS-STAGED + DOUBLE-BUFFERED (1 barrier/iter), u8 abT.
// 1024 blocks x 256 thr = 4 waves; block = ONE head x FOUR q-tiles.
// XCD decode keyed on b: b = m&7. r = m>>3: h = r&7, ts = (r>>3)&1, sg = r>>4.
// kls stride 72 (ushort); vls stride 40 (ushort); abls stride 136 (u8).
// tbl[0..254] = table*log2e, tbl[255] = vbias*log2e (boundary sentinel;
// data values are 0..254 so 255 only means boundary).
// ---------------------------------------------------------------------------
__global__ __launch_bounds__(256)
void attn_fused(const unsigned short* qh, const unsigned short* kh,
                const unsigned short* vht2, const unsigned char* abT,
                const float* bias_table, const float* vbias,
                unsigned short* ctxp, float* lsump)
{
  __shared__ float tbl[256];                // [0..254]=table*log2e, 255=vbias
  __shared__ unsigned short kls[2][32*72];  // K tile [t'][d]
  __shared__ unsigned short vls[2][64*40];  // V tile [d][t']
  __shared__ unsigned char  abls[2][32*136];// ab tile [t'][q 0..127], u8

  const int tid = threadIdx.x;
  const int m   = blockIdx.x;
  const int b   = m & 7;                 // XCD key: all 128 blocks of b co-XCD
  const int r   = m >> 3;
  const int h   = r & 7;
  const int ts  = (r >> 3) & 1;
  const int sg  = r >> 4;                // q-group 0..7
  const int tb  = ts*512;
  const int q0  = sg*128;

  {
    const int i = tid;                   // 256 threads cover 256 entries
    float v = (i < 255) ? bias_table[i*8 + h] : vbias[h];
    tbl[i] = v * 1.4426950408889634f;
  }

  const int w = tid>>6, lane = tid&63, lo = lane&31, hi = lane>>5;
  const bool hib = (hi != 0);
  const int s0 = q0 + w*32;              // this wave's q-tile base

  const unsigned short* qbase  = qh   + (size_t)(b*8+h)*65536;
  const unsigned short* kbase  = kh   + (size_t)(b*8+h)*65536 + (size_t)tb*64;
  const unsigned short* vbase  = vht2 + ((size_t)(b*8+h)*32 + (tb>>5))*2048;
  const unsigned char*  abbase = abT  + ((size_t)b<<20) + q0;

  // Q fragments (B operand; Q[q = s0+lo][d-chunk]) — loaded once
  bf16x8 qf[4];
  #pragma unroll
  for (int kf=0; kf<4; ++kf)
    qf[kf] = *(const bf16x8*)&qbase[(s0+lo)*64 + kf*16 + hi*8];

  f32x16 accv[2]; accv[0] = zero16(); accv[1] = zero16();
  float lsum = 0.0f;

  // staging addresses (coalesced; 16B per thread per structure)
  const int kdst = (tid>>3)*72  + (tid&7)*8;    // K: row t'=tid/8, col d=(tid%8)*8
  const int vdst = (tid>>2)*40  + (tid&3)*8;    // V: row d=tid/4, col t'=(tid%4)*8
  const int adst = (tid>>3)*136 + (tid&7)*16;   // ab u8: row t'=tid/8, 16 q each

  // ---- prologue: load tile 0, stage into buf0, issue tile-1 loads, barrier ----
  uint4 krg, vrg, ar0;
  krg = *(const uint4*)&kbase[tid*8];
  vrg = *(const uint4*)&vbase[tid*8];
  ar0 = *(const uint4*)&abbase[(size_t)(tb + (tid>>3))*1024 + (tid&7)*16];
  *(uint4*)&kls[0][kdst]  = krg;
  *(uint4*)&vls[0][vdst]  = vrg;
  *(uint4*)&abls[0][adst] = ar0;
  krg = *(const uint4*)&kbase[32*64 + tid*8];
  vrg = *(const uint4*)&vbase[2048 + tid*8];
  ar0 = *(const uint4*)&abbase[(size_t)(tb + 32 + (tid>>3))*1024 + (tid&7)*16];
  bar_lgkm();   // buf0 visible (also covers tbl)

  for (int tt=0; tt<512; tt+=32){
    const int cur = (tt>>5) & 1;
    // stage tile tt+32 into the OTHER buffer (vmcnt wait here, ~1 iter slack);
    // that buffer's iter-(tt-32) readers finished before the last barrier.
    *(uint4*)&kls[cur^1][kdst]  = krg;
    *(uint4*)&vls[cur^1][vdst]  = vrg;
    *(uint4*)&abls[cur^1][adst] = ar0;
    // issue loads for tile tt+64 (wrapped; extras on last iters harmless)
    {
      const int tn = (tt+64)&511;
      krg = *(const uint4*)&kbase[tn*64 + tid*8];
      vrg = *(const uint4*)&vbase[(tn>>5)*2048 + tid*8];
      ar0 = *(const uint4*)&abbase[(size_t)(tb + tn + (tid>>3))*1024 + (tid&7)*16];
    }

    // QK^T swapped: sc[r] = S[t = tt + crow(r,hi)][q = s0+lo] (from buf[cur])
    f32x16 sc = zero16();
    #pragma unroll
    for (int kf=0; kf<4; ++kf){
      bf16x8 kfr = *(const bf16x8*)&kls[cur][lo*72 + kf*16 + hi*8];
      sc = __builtin_amdgcn_mfma_f32_32x32x16_bf16(kfr, qf[kf], sc, 0,0,0);
    }

    // bias gather (u8 LDS ab tile) + exp2 + pack
    unsigned d[4][2];
    float ls = 0.0f;
    #pragma unroll
    for (int g=0; g<4; ++g){
      float p[4];
      #pragma unroll
      for (int u=0; u<4; ++u){
        const int crow = u + 8*g + 4*hi;
        const int idx  = abls[cur][crow*136 + w*32 + lo];
        p[u] = __builtin_amdgcn_exp2f(sc[4*g+u] + tbl[idx]);
        ls  += p[u];
      }
      d[g][0] = f2bf_pair(p[0], p[1]);
      d[g][1] = f2bf_pair(p[2], p[3]);
    }
    lsum += ls;

    // exchange with partner lane (lo, 1-hi)
    unsigned x[4][2];
    #pragma unroll
    for (int g=0; g<4; ++g){
      x[g][0] = __shfl_xor(d[g][0], 32, 64);
      x[g][1] = __shfl_xor(d[g][1], 32, 64);
    }

    // PV: A-frag(c2) = hi ? {x[2c2+1], d[2c2+1]} : {d[2c2], x[2c2]}
    #pragma unroll
    for (int c2=0; c2<2; ++c2){
      union { unsigned u[4]; bf16x8 v; } pc;
      pc.u[0] = hib ? x[2*c2+1][0] : d[2*c2][0];
      pc.u[1] = hib ? x[2*c2+1][1] : d[2*c2][1];
      pc.u[2] = hib ? d[2*c2+1][0] : x[2*c2][0];
      pc.u[3] = hib ? d[2*c2+1][1] : x[2*c2][1];
      bf16x8 vf0 = *(const bf16x8*)&vls[cur][(     lo)*40 + c2*16 + hi*8];
      bf16x8 vf1 = *(const bf16x8*)&vls[cur][(32 + lo)*40 + c2*16 + hi*8];
      accv[0] = __builtin_amdgcn_mfma_f32_32x32x16_bf16(pc.v, vf0, accv[0], 0,0,0);
      accv[1] = __builtin_amdgcn_mfma_f32_32x32x16_bf16(pc.v, vf1, accv[1], 0,0,0);
    }
    // ONE barrier: my reads of buf[cur] + writes of buf[cur^1] all drained
    bar_lgkm();
  }

  // full partial row sum for q = s0+lo (combine the two hi-halves)
  lsum += __shfl_xor(lsum, 32, 64);

  // store UNNORMALIZED partial ctx bf16 (rows q = crow(r,hi), col d = lo)
  unsigned short* cbase = ctxp + (size_t)ts*4194304;   // 8*1024*512 per half
  #pragma unroll
  for (int dc=0; dc<2; ++dc){
    #pragma unroll
    for (int r2=0;r2<16;r2++){
      const int rq = (r2&3) + 8*(r2>>2) + 4*hi;
      cbase[((size_t)b*1024 + s0 + rq)*512 + h*64 + dc*32 + lo] = f2bf(accv[dc][r2]);
    }
  }
  if (hi == 0){
    lsump[((size_t)(ts*8 + b)*8 + h)*1024 + s0 + lo] = lsum;
  }
}

extern "C" void kernel_launch(void* const* d_in, const int* in_sizes, int n_in,
                              void* d_out, int out_size, void* d_ws, size_t ws_size,
                              hipStream_t stream)
{
  const float* q    = (const float*)d_in[0];
  const float* k    = (const float*)d_in[1];
  const float* v    = (const float*)d_in[2];
  const int*   ab   = (const int*)  d_in[3];
  const float* Wq   = (const float*)d_in[4];
  const float* bq   = (const float*)d_in[5];
  const float* Wk   = (const float*)d_in[6];
  const float* bk   = (const float*)d_in[7];
  const float* Wv   = (const float*)d_in[8];
  const float* bv   = (const float*)d_in[9];
  const float* Wo   = (const float*)d_in[10];
  const float* bo   = (const float*)d_in[11];
  const float* btab = (const float*)d_in[12];
  const float* vbia = (const float*)d_in[13];

  char* ws = (char*)d_ws;
  unsigned short* qh   = (unsigned short*)(ws);                    //  8 MB
  unsigned short* kh   = (unsigned short*)(ws + ((size_t) 8<<20)); //  8 MB
  unsigned short* vht2 = (unsigned short*)(ws + ((size_t)16<<20)); //  8 MB
  unsigned short* ctxp = (unsigned short*)(ws + ((size_t)24<<20)); // 16 MB (2 halves)
  float*          lsmp = (float*)         (ws + ((size_t)40<<20)); // 512 KB
  unsigned char*  abT  = (unsigned char*) (ws + ((size_t)41<<20)); //  8 MB (u8)

  const float SCALE_Q = 0.125f * 1.4426950408889634f;  // D^-0.5 * log2(e)

  qkv_trans<<<2816, 256, 0, stream>>>(q, k, v, Wq, Wk, Wv, bq, bk, bv, ab,
                                      qh, kh, vht2, abT, SCALE_Q);
  attn_fused<<<1024, 256, 0, stream>>>(qh, kh, vht2, abT, btab, vbia,
                                       ctxp, lsmp);
  out_proj<<<dim3(64,4), 256, 0, stream>>>(ctxp, ctxp + (size_t)4194304,
                                           lsmp, Wo, bo, (float*)d_out);
}

// Round 33
// 121.398 us; speedup vs baseline: 1.1807x; 1.1807x over previous
//
#include <hip/hip_runtime.h>
#include <hip/hip_bf16.h>

// MultiHeadAttention fused pipeline, MI355X gfx950.  SESSION-BEST CONFIG (R31).
// B=8, S=1024 (N=1023 + 1 global), HID=512, H=8, D=64.
// Stages: qkv_proj (128x128 dbuf 1-barrier) -> qh/kh [B][H][S][D], vht2 blocked;
//         ab_transpose -> abT u8 [B][1024t][1024q] (255 = boundary sentinel);
//         attn_fused (LDS-staged, dbuf, b-keyed XCD clustering) -> partials;
//         out_proj fuses partial-combine + normalize -> f32 out.
// Ladder: 194 -> 148 -> 128.2 -> 127.8 -> 125.9 -> 124.6 -> 121.3 (R31 u8 abT).
// R32 post-mortem: qkv+transpose single-kernel MERGE regressed 2x (103.9us
//   merged; MfmaUtil 4.7%, VGPR 92): heterogeneous block-type merge poisoned
//   the qkv hot-loop codegen + displaced residency. Lesson: bubble-filling
//   requires the bubble owner's code untouched -> impossible in one kernel.
// R33: exact revert to R31 (best measured, confirmed structure). qkv is
//   latency-structural (52us vs 14us BW floor, 4 levers falsified); attn is
//   VALU-chain bound; transpose/out_proj near floor. Hold here.

typedef __attribute__((ext_vector_type(8)))  __bf16 bf16x8;
typedef __attribute__((ext_vector_type(16))) float  f32x16;

__device__ inline f32x16 zero16(){
  f32x16 z;
  #pragma unroll
  for (int i=0;i<16;i++) z[i] = 0.0f;
  return z;
}

__device__ inline unsigned short f2bf(float x){           // RNE f32->bf16
  unsigned u = __float_as_uint(x);
  u += 0x7fffu + ((u>>16)&1u);
  return (unsigned short)(u>>16);
}
__device__ inline unsigned f2bf_pair(float a, float b){   // pack 2 bf16 into dword (RNE)
  unsigned ua = __float_as_uint(a); ua += 0x7fffu + ((ua>>16)&1u);
  unsigned ub = __float_as_uint(b); ub += 0x7fffu + ((ub>>16)&1u);
  return (ua>>16) | (ub & 0xffff0000u);
}
// combine two packed-bf16 dwords: (a+b)*rn per element, repacked bf16
__device__ inline unsigned comb2(unsigned a, unsigned b, float rn){
  const float a0 = __uint_as_float(a<<16), a1 = __uint_as_float(a & 0xffff0000u);
  const float b0 = __uint_as_float(b<<16), b1 = __uint_as_float(b & 0xffff0000u);
  return f2bf_pair((a0+b0)*rn, (a1+b1)*rn);
}

__device__ inline void bar_lgkm(){   // LDS-visibility barrier WITHOUT vmcnt drain
  asm volatile("s_waitcnt lgkmcnt(0)" ::: "memory");
  __builtin_amdgcn_s_barrier();
}

// ---------------------------------------------------------------------------
// ab transpose: abT[b][t][q] = (q<1023 && t<1023) ? (u8)ab[b][q][t] : 255.
// 255 = boundary sentinel (vbias); data values are 0..254 (randint exclusive).
// 2048 blocks x 256 thr, 64x64 tile via LDS (65-pad).
// ---------------------------------------------------------------------------
__global__ __launch_bounds__(256)
void ab_transpose(const int* ab, unsigned char* abT)
{
  __shared__ int tl[64*65];
  const int k  = blockIdx.x;
  const int b  = k >> 8;
  const int ti = k & 255;
  const int t0 = (ti & 15) << 6, q0 = (ti >> 4) << 6;
  const int c  = threadIdx.x & 63, r0 = threadIdx.x >> 6;
  #pragma unroll
  for (int rp = 0; rp < 16; ++rp){
    const int r = r0 + rp*4;
    const int q = q0 + r, t = t0 + c;
    int v = 255;
    if (q < 1023 && t < 1023) v = ab[((size_t)b*1023 + q)*1023 + t];
    tl[r*65 + c] = v;
  }
  __syncthreads();
  unsigned char* dst = abT + ((size_t)b << 20);
  #pragma unroll
  for (int rp = 0; rp < 16; ++rp){
    const int r = r0 + rp*4;               // r = t offset, c = q offset
    dst[(size_t)(t0 + r)*1024 + q0 + c] = (unsigned char)tl[c*65 + r];
  }
}

// ---------------------------------------------------------------------------
// Merged Q/K/V projection. 768 blocks, 256 threads, 128x128 tile,
// DOUBLE-BUFFERED LDS, ONE barrier per K-step (R26-proven).
// sel=0: qh = (q Wq^T + bq)*scaleq   [B][H][S][D]
// sel=1: kh = (k Wk^T + bk)          [B][H][S][D]
// sel=2: vht2 = (v Wv^T + bv) tile-blocked [B][H][S/32][D][32]
// ---------------------------------------------------------------------------
__global__ __launch_bounds__(256)
void qkv_proj(const float* xq, const float* xk, const float* xv,
              const float* Wq, const float* Wk, const float* Wv,
              const float* bq, const float* bk, const float* bv,
              unsigned short* qh, unsigned short* kh, unsigned short* vht2,
              float scaleq)
{
  __shared__ unsigned short lda[2][128*40];   // 40-pad rows
  __shared__ unsigned short ldb[2][128*40];
  const int bid = blockIdx.x;
  const int sel = bid >> 8;                // uniform per block
  const int t   = bid & 255;
  const float *RA, *RB, *bias;
  int r0, c0;
  if (sel == 0){ RA = xq; RB = Wq; bias = bq; r0 = (t&63)*128; c0 = (t>>6)*128; }
  else if (sel == 1){ RA = xk; RB = Wk; bias = bk; r0 = (t&63)*128; c0 = (t>>6)*128; }
  else { RA = Wv; RB = xv; bias = bv; r0 = (t&3)*128; c0 = (t>>2)*128; }

  const int tid  = threadIdx.x;
  const int w    = tid>>6, lane = tid&63, lo = lane&31, hi = lane>>5;
  const int wr   = (w>>1)*64, wc = (w&1)*64;
  const int arow = tid>>1, kb = (tid&1)*16;

  f32x16 acc[2][2];
  #pragma unroll
  for (int i=0;i<2;i++)
    #pragma unroll
    for (int j=0;j<2;j++) acc[i][j] = zero16();

  float4 ra[4], rb4[4];

  // ---- prologue: load tile0; stage into buf0; load tile1; barrier ----
  {
    const float4* p = (const float4*)(RA + (r0+arow)*512 + kb);
    ra[0]=p[0]; ra[1]=p[1]; ra[2]=p[2]; ra[3]=p[3];
    const float4* pq = (const float4*)(RB + (c0+arow)*512 + kb);
    rb4[0]=pq[0]; rb4[1]=pq[1]; rb4[2]=pq[2]; rb4[3]=pq[3];
  }
  {
    uint4 w0, w1;
    w0.x = f2bf_pair(ra[0].x, ra[0].y); w0.y = f2bf_pair(ra[0].z, ra[0].w);
    w0.z = f2bf_pair(ra[1].x, ra[1].y); w0.w = f2bf_pair(ra[1].z, ra[1].w);
    w1.x = f2bf_pair(ra[2].x, ra[2].y); w1.y = f2bf_pair(ra[2].z, ra[2].w);
    w1.z = f2bf_pair(ra[3].x, ra[3].y); w1.w = f2bf_pair(ra[3].z, ra[3].w);
    uint4* pa = (uint4*)&lda[0][arow*40 + kb];
    pa[0] = w0; pa[1] = w1;
    uint4 v0, v1;
    v0.x = f2bf_pair(rb4[0].x, rb4[0].y); v0.y = f2bf_pair(rb4[0].z, rb4[0].w);
    v0.z = f2bf_pair(rb4[1].x, rb4[1].y); v0.w = f2bf_pair(rb4[1].z, rb4[1].w);
    v1.x = f2bf_pair(rb4[2].x, rb4[2].y); v1.y = f2bf_pair(rb4[2].z, rb4[2].w);
    v1.z = f2bf_pair(rb4[3].x, rb4[3].y); v1.w = f2bf_pair(rb4[3].z, rb4[3].w);
    uint4* pb = (uint4*)&ldb[0][arow*40 + kb];
    pb[0] = v0; pb[1] = v1;
  }
  {
    const float4* p = (const float4*)(RA + (r0+arow)*512 + 32 + kb);
    ra[0]=p[0]; ra[1]=p[1]; ra[2]=p[2]; ra[3]=p[3];
    const float4* pq = (const float4*)(RB + (c0+arow)*512 + 32 + kb);
    rb4[0]=pq[0]; rb4[1]=pq[1]; rb4[2]=pq[2]; rb4[3]=pq[3];
  }
  bar_lgkm();   // buf0 visible

  for (int ks=0; ks<16; ++ks){
    const int cur = ks & 1;
    // stage tile ks+1 into the OTHER buffer (regs loaded last iter)
    if (ks < 15){
      uint4 w0, w1;
      w0.x = f2bf_pair(ra[0].x, ra[0].y); w0.y = f2bf_pair(ra[0].z, ra[0].w);
      w0.z = f2bf_pair(ra[1].x, ra[1].y); w0.w = f2bf_pair(ra[1].z, ra[1].w);
      w1.x = f2bf_pair(ra[2].x, ra[2].y); w1.y = f2bf_pair(ra[2].z, ra[2].w);
      w1.z = f2bf_pair(ra[3].x, ra[3].y); w1.w = f2bf_pair(ra[3].z, ra[3].w);
      uint4* pa = (uint4*)&lda[cur^1][arow*40 + kb];
      pa[0] = w0; pa[1] = w1;
      uint4 v0, v1;
      v0.x = f2bf_pair(rb4[0].x, rb4[0].y); v0.y = f2bf_pair(rb4[0].z, rb4[0].w);
      v0.z = f2bf_pair(rb4[1].x, rb4[1].y); v0.w = f2bf_pair(rb4[1].z, rb4[1].w);
      v1.x = f2bf_pair(rb4[2].x, rb4[2].y); v1.y = f2bf_pair(rb4[2].z, rb4[2].w);
      v1.z = f2bf_pair(rb4[3].x, rb4[3].y); v1.w = f2bf_pair(rb4[3].z, rb4[3].w);
      uint4* pb = (uint4*)&ldb[cur^1][arow*40 + kb];
      pb[0] = v0; pb[1] = v1;
    }
    // issue loads for tile ks+2 (in flight across the barrier)
    if (ks < 14){
      const int k0 = (ks+2)*32;
      const float4* p = (const float4*)(RA + (r0+arow)*512 + k0 + kb);
      ra[0]=p[0]; ra[1]=p[1]; ra[2]=p[2]; ra[3]=p[3];
      const float4* pq = (const float4*)(RB + (c0+arow)*512 + k0 + kb);
      rb4[0]=pq[0]; rb4[1]=pq[1]; rb4[2]=pq[2]; rb4[3]=pq[3];
    }
    // MFMA from current buffer (visible via previous barrier)
    #pragma unroll
    for (int kf=0; kf<2; ++kf){
      bf16x8 af0 = *(const bf16x8*)&lda[cur][(wr+lo)*40    + kf*16 + hi*8];
      bf16x8 af1 = *(const bf16x8*)&lda[cur][(wr+32+lo)*40 + kf*16 + hi*8];
      bf16x8 bg0 = *(const bf16x8*)&ldb[cur][(wc+lo)*40    + kf*16 + hi*8];
      bf16x8 bg1 = *(const bf16x8*)&ldb[cur][(wc+32+lo)*40 + kf*16 + hi*8];
      acc[0][0] = __builtin_amdgcn_mfma_f32_32x32x16_bf16(af0, bg0, acc[0][0], 0,0,0);
      acc[0][1] = __builtin_amdgcn_mfma_f32_32x32x16_bf16(af0, bg1, acc[0][1], 0,0,0);
      acc[1][0] = __builtin_amdgcn_mfma_f32_32x32x16_bf16(af1, bg0, acc[1][0], 0,0,0);
      acc[1][1] = __builtin_amdgcn_mfma_f32_32x32x16_bf16(af1, bg1, acc[1][1], 0,0,0);
    }
    // ONE barrier: my reads of buf[cur] + writes of buf[cur^1] all drained
    bar_lgkm();
  }

  // epilogue; C/D layout: col = lane&31, row = (r&3)+8*(r>>2)+4*(lane>>5)
  #pragma unroll
  for (int mi=0;mi<2;mi++){
    #pragma unroll
    for (int ni=0;ni<2;ni++){
      #pragma unroll
      for (int r=0;r<16;r++){
        const int rl = wr + mi*32 + (r&3) + 8*(r>>2) + 4*hi;
        const int cl = wc + ni*32 + lo;
        const int rg = r0 + rl, cg = c0 + cl;
        float v = acc[mi][ni][r];
        if (sel == 0){
          v = (v + bias[cg]) * scaleq;
          const int bb = rg>>10, s = rg&1023, h = cg>>6, d = cg&63;
          qh[(((bb*8+h)*1024)+s)*64 + d] = f2bf(v);
        } else if (sel == 1){
          v = v + bias[cg];
          const int bb = rg>>10, s = rg&1023, h = cg>>6, d = cg&63;
          kh[(((bb*8+h)*1024)+s)*64 + d] = f2bf(v);
        } else {
          v = v + bias[rg];
          const int h = rg>>6, d = rg&63, bb = cg>>10, s = cg&1023;
          vht2[(((size_t)(bb*8+h)*32 + (s>>5))*64 + d)*32 + (s&31)] = f2bf(v);
        }
      }
    }
  }
}

// ---------------------------------------------------------------------------
// Out projection with fused partial-combine:
//   A[row][k] = (ctx0[row][k] + ctx1[row][k]) / (l0[b,h,s] + l1[b,h,s])
//   out[8192][512] = A Wo^T + bo (f32).
// ---------------------------------------------------------------------------
__global__ __launch_bounds__(256)
void out_proj(const unsigned short* ctx0, const unsigned short* ctx1,
              const float* lsump, const float* Wo, const float* bo, float* OUT)
{
  __shared__ unsigned short lda[128*40];
  __shared__ unsigned short ldb[128*40];
  const int tid  = threadIdx.x;
  const int r0   = blockIdx.x*128, c0 = blockIdx.y*128;
  const int w    = tid>>6, lane = tid&63, lo = lane&31, hi = lane>>5;
  const int wr   = (w>>1)*64, wc = (w&1)*64;
  const int arow = tid>>1, kb = (tid&1)*16;
  const int rgs  = r0 + arow, bb = rgs>>10, ss = rgs&1023;
  const float* lb0 = lsump + (size_t)(bb*8)*1024 + ss;        // ts=0, + h*1024
  const float* lb1 = lsump + (size_t)((8+bb)*8)*1024 + ss;    // ts=1

  f32x16 acc[2][2];
  #pragma unroll
  for (int i=0;i<2;i++)
    #pragma unroll
    for (int j=0;j<2;j++) acc[i][j] = zero16();

  uint4 ra0[2], ra1[2];
  float4 rb4[4];
  float l0, l1;

  {
    const uint4* p0 = (const uint4*)(ctx0 + rgs*512 + kb);
    ra0[0]=p0[0]; ra0[1]=p0[1];
    const uint4* p1 = (const uint4*)(ctx1 + rgs*512 + kb);
    ra1[0]=p1[0]; ra1[1]=p1[1];
    const int h = kb>>6;
    l0 = lb0[h*1024]; l1 = lb1[h*1024];
    const float4* pq = (const float4*)(Wo + (c0+arow)*512 + kb);
    rb4[0]=pq[0]; rb4[1]=pq[1]; rb4[2]=pq[2]; rb4[3]=pq[3];
  }

  for (int ks=0; ks<16; ++ks){
    bar_lgkm();
    {
      const float rn = __builtin_amdgcn_rcpf(l0 + l1);
      uint4 w0, w1;
      w0.x = comb2(ra0[0].x, ra1[0].x, rn); w0.y = comb2(ra0[0].y, ra1[0].y, rn);
      w0.z = comb2(ra0[0].z, ra1[0].z, rn); w0.w = comb2(ra0[0].w, ra1[0].w, rn);
      w1.x = comb2(ra0[1].x, ra1[1].x, rn); w1.y = comb2(ra0[1].y, ra1[1].y, rn);
      w1.z = comb2(ra0[1].z, ra1[1].z, rn); w1.w = comb2(ra0[1].w, ra1[1].w, rn);
      uint4* pa = (uint4*)&lda[arow*40 + kb];
      pa[0] = w0; pa[1] = w1;
      uint4 v0, v1;
      v0.x = f2bf_pair(rb4[0].x, rb4[0].y); v0.y = f2bf_pair(rb4[0].z, rb4[0].w);
      v0.z = f2bf_pair(rb4[1].x, rb4[1].y); v0.w = f2bf_pair(rb4[1].z, rb4[1].w);
      v1.x = f2bf_pair(rb4[2].x, rb4[2].y); v1.y = f2bf_pair(rb4[2].z, rb4[2].w);
      v1.z = f2bf_pair(rb4[3].x, rb4[3].y); v1.w = f2bf_pair(rb4[3].z, rb4[3].w);
      uint4* pb = (uint4*)&ldb[arow*40 + kb];
      pb[0] = v0; pb[1] = v1;
    }
    if (ks < 15){
      const int k0 = (ks+1)*32;
      const uint4* p0 = (const uint4*)(ctx0 + rgs*512 + k0 + kb);
      ra0[0]=p0[0]; ra0[1]=p0[1];
      const uint4* p1 = (const uint4*)(ctx1 + rgs*512 + k0 + kb);
      ra1[0]=p1[0]; ra1[1]=p1[1];
      const int h = (k0+kb)>>6;
      l0 = lb0[h*1024]; l1 = lb1[h*1024];
      const float4* pq = (const float4*)(Wo + (c0+arow)*512 + k0 + kb);
      rb4[0]=pq[0]; rb4[1]=pq[1]; rb4[2]=pq[2]; rb4[3]=pq[3];
    }
    bar_lgkm();
    #pragma unroll
    for (int kf=0; kf<2; ++kf){
      bf16x8 af0 = *(const bf16x8*)&lda[(wr+lo)*40    + kf*16 + hi*8];
      bf16x8 af1 = *(const bf16x8*)&lda[(wr+32+lo)*40 + kf*16 + hi*8];
      bf16x8 bg0 = *(const bf16x8*)&ldb[(wc+lo)*40    + kf*16 + hi*8];
      bf16x8 bg1 = *(const bf16x8*)&ldb[(wc+32+lo)*40 + kf*16 + hi*8];
      acc[0][0] = __builtin_amdgcn_mfma_f32_32x32x16_bf16(af0, bg0, acc[0][0], 0,0,0);
      acc[0][1] = __builtin_amdgcn_mfma_f32_32x32x16_bf16(af0, bg1, acc[0][1], 0,0,0);
      acc[1][0] = __builtin_amdgcn_mfma_f32_32x32x16_bf16(af1, bg0, acc[1][0], 0,0,0);
      acc[1][1] = __builtin_amdgcn_mfma_f32_32x32x16_bf16(af1, bg1, acc[1][1], 0,0,0);
    }
  }

  #pragma unroll
  for (int mi=0;mi<2;mi++){
    #pragma unroll
    for (int ni=0;ni<2;ni++){
      #pragma unroll
      for (int r=0;r<16;r++){
        const int rl = wr + mi*32 + (r&3) + 8*(r>>2) + 4*hi;
        const int cl = wc + ni*32 + lo;
        const int rg = r0 + rl, cg = c0 + cl;
        OUT[rg*512 + cg] = acc[mi][ni][r] + bo[cg];
      }
    }
  }
}

// ---------------------------------------------------------------------------
// Fused attention, LDS-STAGED + DOUBLE-BUFFERED (1 barrier/iter), u8 abT.
// 1024 blocks x 256 thr = 4 waves; block = ONE head x FOUR q-tiles.
// XCD decode keyed on b: b = m&7. r = m>>3: h = r&7, ts = (r>>3)&1, sg = r>>4.
// kls stride 72 (ushort); vls stride 40 (ushort); abls stride 136 (u8).
// tbl[0..254] = table*log2e, tbl[255] = vbias*log2e (boundary sentinel;
// data values are 0..254 so 255 only means boundary).
// ---------------------------------------------------------------------------
__global__ __launch_bounds__(256)
void attn_fused(const unsigned short* qh, const unsigned short* kh,
                const unsigned short* vht2, const unsigned char* abT,
                const float* bias_table, const float* vbias,
                unsigned short* ctxp, float* lsump)
{
  __shared__ float tbl[256];                // [0..254]=table*log2e, 255=vbias
  __shared__ unsigned short kls[2][32*72];  // K tile [t'][d]
  __shared__ unsigned short vls[2][64*40];  // V tile [d][t']
  __shared__ unsigned char  abls[2][32*136];// ab tile [t'][q 0..127], u8

  const int tid = threadIdx.x;
  const int m   = blockIdx.x;
  const int b   = m & 7;                 // XCD key: all 128 blocks of b co-XCD
  const int r   = m >> 3;
  const int h   = r & 7;
  const int ts  = (r >> 3) & 1;
  const int sg  = r >> 4;                // q-group 0..7
  const int tb  = ts*512;
  const int q0  = sg*128;

  {
    const int i = tid;                   // 256 threads cover 256 entries
    float v = (i < 255) ? bias_table[i*8 + h] : vbias[h];
    tbl[i] = v * 1.4426950408889634f;
  }

  const int w = tid>>6, lane = tid&63, lo = lane&31, hi = lane>>5;
  const bool hib = (hi != 0);
  const int s0 = q0 + w*32;              // this wave's q-tile base

  const unsigned short* qbase  = qh   + (size_t)(b*8+h)*65536;
  const unsigned short* kbase  = kh   + (size_t)(b*8+h)*65536 + (size_t)tb*64;
  const unsigned short* vbase  = vht2 + ((size_t)(b*8+h)*32 + (tb>>5))*2048;
  const unsigned char*  abbase = abT  + ((size_t)b<<20) + q0;

  // Q fragments (B operand; Q[q = s0+lo][d-chunk]) — loaded once
  bf16x8 qf[4];
  #pragma unroll
  for (int kf=0; kf<4; ++kf)
    qf[kf] = *(const bf16x8*)&qbase[(s0+lo)*64 + kf*16 + hi*8];

  f32x16 accv[2]; accv[0] = zero16(); accv[1] = zero16();
  float lsum = 0.0f;

  // staging addresses (coalesced; 16B per thread per structure)
  const int kdst = (tid>>3)*72  + (tid&7)*8;    // K: row t'=tid/8, col d=(tid%8)*8
  const int vdst = (tid>>2)*40  + (tid&3)*8;    // V: row d=tid/4, col t'=(tid%4)*8
  const int adst = (tid>>3)*136 + (tid&7)*16;   // ab u8: row t'=tid/8, 16 q each

  // ---- prologue: load tile 0, stage into buf0, issue tile-1 loads, barrier ----
  uint4 krg, vrg, ar0;
  krg = *(const uint4*)&kbase[tid*8];
  vrg = *(const uint4*)&vbase[tid*8];
  ar0 = *(const uint4*)&abbase[(size_t)(tb + (tid>>3))*1024 + (tid&7)*16];
  *(uint4*)&kls[0][kdst]  = krg;
  *(uint4*)&vls[0][vdst]  = vrg;
  *(uint4*)&abls[0][adst] = ar0;
  krg = *(const uint4*)&kbase[32*64 + tid*8];
  vrg = *(const uint4*)&vbase[2048 + tid*8];
  ar0 = *(const uint4*)&abbase[(size_t)(tb + 32 + (tid>>3))*1024 + (tid&7)*16];
  bar_lgkm();   // buf0 visible (also covers tbl)

  for (int tt=0; tt<512; tt+=32){
    const int cur = (tt>>5) & 1;
    // stage tile tt+32 into the OTHER buffer (vmcnt wait here, ~1 iter slack);
    // that buffer's iter-(tt-32) readers finished before the last barrier.
    *(uint4*)&kls[cur^1][kdst]  = krg;
    *(uint4*)&vls[cur^1][vdst]  = vrg;
    *(uint4*)&abls[cur^1][adst] = ar0;
    // issue loads for tile tt+64 (wrapped; extras on last iters harmless)
    {
      const int tn = (tt+64)&511;
      krg = *(const uint4*)&kbase[tn*64 + tid*8];
      vrg = *(const uint4*)&vbase[(tn>>5)*2048 + tid*8];
      ar0 = *(const uint4*)&abbase[(size_t)(tb + tn + (tid>>3))*1024 + (tid&7)*16];
    }

    // QK^T swapped: sc[r] = S[t = tt + crow(r,hi)][q = s0+lo] (from buf[cur])
    f32x16 sc = zero16();
    #pragma unroll
    for (int kf=0; kf<4; ++kf){
      bf16x8 kfr = *(const bf16x8*)&kls[cur][lo*72 + kf*16 + hi*8];
      sc = __builtin_amdgcn_mfma_f32_32x32x16_bf16(kfr, qf[kf], sc, 0,0,0);
    }

    // bias gather (u8 LDS ab tile) + exp2 + pack
    unsigned d[4][2];
    float ls = 0.0f;
    #pragma unroll
    for (int g=0; g<4; ++g){
      float p[4];
      #pragma unroll
      for (int u=0; u<4; ++u){
        const int crow = u + 8*g + 4*hi;
        const int idx  = abls[cur][crow*136 + w*32 + lo];
        p[u] = __builtin_amdgcn_exp2f(sc[4*g+u] + tbl[idx]);
        ls  += p[u];
      }
      d[g][0] = f2bf_pair(p[0], p[1]);
      d[g][1] = f2bf_pair(p[2], p[3]);
    }
    lsum += ls;

    // exchange with partner lane (lo, 1-hi)
    unsigned x[4][2];
    #pragma unroll
    for (int g=0; g<4; ++g){
      x[g][0] = __shfl_xor(d[g][0], 32, 64);
      x[g][1] = __shfl_xor(d[g][1], 32, 64);
    }

    // PV: A-frag(c2) = hi ? {x[2c2+1], d[2c2+1]} : {d[2c2], x[2c2]}
    #pragma unroll
    for (int c2=0; c2<2; ++c2){
      union { unsigned u[4]; bf16x8 v; } pc;
      pc.u[0] = hib ? x[2*c2+1][0] : d[2*c2][0];
      pc.u[1] = hib ? x[2*c2+1][1] : d[2*c2][1];
      pc.u[2] = hib ? d[2*c2+1][0] : x[2*c2][0];
      pc.u[3] = hib ? d[2*c2+1][1] : x[2*c2][1];
      bf16x8 vf0 = *(const bf16x8*)&vls[cur][(     lo)*40 + c2*16 + hi*8];
      bf16x8 vf1 = *(const bf16x8*)&vls[cur][(32 + lo)*40 + c2*16 + hi*8];
      accv[0] = __builtin_amdgcn_mfma_f32_32x32x16_bf16(pc.v, vf0, accv[0], 0,0,0);
      accv[1] = __builtin_amdgcn_mfma_f32_32x32x16_bf16(pc.v, vf1, accv[1], 0,0,0);
    }
    // ONE barrier: my reads of buf[cur] + writes of buf[cur^1] all drained
    bar_lgkm();
  }

  // full partial row sum for q = s0+lo (combine the two hi-halves)
  lsum += __shfl_xor(lsum, 32, 64);

  // store UNNORMALIZED partial ctx bf16 (rows q = crow(r,hi), col d = lo)
  unsigned short* cbase = ctxp + (size_t)ts*4194304;   // 8*1024*512 per half
  #pragma unroll
  for (int dc=0; dc<2; ++dc){
    #pragma unroll
    for (int r2=0;r2<16;r2++){
      const int rq = (r2&3) + 8*(r2>>2) + 4*hi;
      cbase[((size_t)b*1024 + s0 + rq)*512 + h*64 + dc*32 + lo] = f2bf(accv[dc][r2]);
    }
  }
  if (hi == 0){
    lsump[((size_t)(ts*8 + b)*8 + h)*1024 + s0 + lo] = lsum;
  }
}

extern "C" void kernel_launch(void* const* d_in, const int* in_sizes, int n_in,
                              void* d_out, int out_size, void* d_ws, size_t ws_size,
                              hipStream_t stream)
{
  const float* q    = (const float*)d_in[0];
  const float* k    = (const float*)d_in[1];
  const float* v    = (const float*)d_in[2];
  const int*   ab   = (const int*)  d_in[3];
  const float* Wq   = (const float*)d_in[4];
  const float* bq   = (const float*)d_in[5];
  const float* Wk   = (const float*)d_in[6];
  const float* bk   = (const float*)d_in[7];
  const float* Wv   = (const float*)d_in[8];
  const float* bv   = (const float*)d_in[9];
  const float* Wo   = (const float*)d_in[10];
  const float* bo   = (const float*)d_in[11];
  const float* btab = (const float*)d_in[12];
  const float* vbia = (const float*)d_in[13];

  char* ws = (char*)d_ws;
  unsigned short* qh   = (unsigned short*)(ws);                    //  8 MB
  unsigned short* kh   = (unsigned short*)(ws + ((size_t) 8<<20)); //  8 MB
  unsigned short* vht2 = (unsigned short*)(ws + ((size_t)16<<20)); //  8 MB
  unsigned short* ctxp = (unsigned short*)(ws + ((size_t)24<<20)); // 16 MB (2 halves)
  float*          lsmp = (float*)         (ws + ((size_t)40<<20)); // 512 KB
  unsigned char*  abT  = (unsigned char*) (ws + ((size_t)41<<20)); //  8 MB (u8)

  const float SCALE_Q = 0.125f * 1.4426950408889634f;  // D^-0.5 * log2(e)

  qkv_proj<<<768, 256, 0, stream>>>(q, k, v, Wq, Wk, Wv, bq, bk, bv,
                                    qh, kh, vht2, SCALE_Q);
  ab_transpose<<<2048, 256, 0, stream>>>(ab, abT);
  attn_fused<<<1024, 256, 0, stream>>>(qh, kh, vht2, abT, btab, vbia,
                                       ctxp, lsmp);
  out_proj<<<dim3(64,4), 256, 0, stream>>>(ctxp, ctxp + (size_t)4194304,
                                           lsmp, Wo, bo, (float*)d_out);
}

// Round 34
// 121.125 us; speedup vs baseline: 1.1834x; 1.0023x over previous
//
#include <hip/hip_runtime.h>
#include <hip/hip_bf16.h>

// MultiHeadAttention fused pipeline, MI355X gfx950.
// B=8, S=1024 (N=1023 + 1 global), HID=512, H=8, D=64.
// Stages: qkv_proj (128x128 dbuf 1-barrier) -> qh/kh [B][H][S][D], vht2 blocked;
//         ab_u8 (streaming narrow, NO transpose) -> ab8 u8 [B][1024q][1024t];
//         attn_fused (LDS-staged, dbuf, b-keyed XCD, [q][t'] ab tile) -> partials;
//         out_proj fuses partial-combine + normalize -> f32 out.
// Ladder: 194 -> 148 -> 128.2 -> 127.8 -> 125.9 -> 124.6 -> 121.3 (u8 abT).
// R34: kill the layout mismatch in the bias gather. Each thread's 16 score
//   elements have q FIXED, t' VARYING (crow = u+8g+4hi), so the old [t'][q]
//   LDS tile forced 16 stride-136 ds_read_u8/thread/iter. New [q][t'] tile:
//   4 consecutive bytes per g -> 4 ds_read_b32 + byte extracts (12 fewer LDS
//   issues). Natural source is ab[b][q][t] -> transpose kernel replaced by
//   pure streaming u8 narrow (ab8, sentinel 255 at q/t>=1023, ~7us floor).
//   Staging: 2 thr/row x 128 rows, 16B each; LDS stride 36 (9r mod 32 -> 2-way
//   free). MFMA/dbuf loop untouched. Gate: attn>51us or total>=121.4 => revert.

typedef __attribute__((ext_vector_type(8)))  __bf16 bf16x8;
typedef __attribute__((ext_vector_type(16))) float  f32x16;

__device__ inline f32x16 zero16(){
  f32x16 z;
  #pragma unroll
  for (int i=0;i<16;i++) z[i] = 0.0f;
  return z;
}

__device__ inline unsigned short f2bf(float x){           // RNE f32->bf16
  unsigned u = __float_as_uint(x);
  u += 0x7fffu + ((u>>16)&1u);
  return (unsigned short)(u>>16);
}
__device__ inline unsigned f2bf_pair(float a, float b){   // pack 2 bf16 into dword (RNE)
  unsigned ua = __float_as_uint(a); ua += 0x7fffu + ((ua>>16)&1u);
  unsigned ub = __float_as_uint(b); ub += 0x7fffu + ((ub>>16)&1u);
  return (ua>>16) | (ub & 0xffff0000u);
}
// combine two packed-bf16 dwords: (a+b)*rn per element, repacked bf16
__device__ inline unsigned comb2(unsigned a, unsigned b, float rn){
  const float a0 = __uint_as_float(a<<16), a1 = __uint_as_float(a & 0xffff0000u);
  const float b0 = __uint_as_float(b<<16), b1 = __uint_as_float(b & 0xffff0000u);
  return f2bf_pair((a0+b0)*rn, (a1+b1)*rn);
}

__device__ inline void bar_lgkm(){   // LDS-visibility barrier WITHOUT vmcnt drain
  asm volatile("s_waitcnt lgkmcnt(0)" ::: "memory");
  __builtin_amdgcn_s_barrier();
}

// ---------------------------------------------------------------------------
// ab_u8: ab8[b][q][t] = (q<1023 && t<1023) ? (u8)ab[b][q][t] : 255.
// NO transpose, NO LDS: pure streaming narrow. 2048 blocks x 256 thr;
// block = (b, 4 rows); one wave per row; thread packs 4 u32 outputs
// (dword index j+64i), reads 4 ints each (16-segment/instr pattern).
// ---------------------------------------------------------------------------
__global__ __launch_bounds__(256)
void ab_u8(const int* ab, unsigned char* ab8)
{
  const int k   = blockIdx.x;          // 2048 = 8 b x 256 row-groups
  const int b   = k >> 8;
  const int q   = ((k & 255) << 2) + (threadIdx.x >> 6);
  const int j   = threadIdx.x & 63;
  const bool qok = (q < 1023);
  const int* rowp = ab + ((size_t)b*1023 + q)*1023;
  unsigned char* outp = ab8 + ((size_t)b << 20) + (size_t)q*1024;
  #pragma unroll
  for (int i = 0; i < 4; ++i){
    const int t0 = (j + 64*i)*4;       // out byte base 0..1020
    unsigned o = 0;
    #pragma unroll
    for (int c = 0; c < 4; ++c){
      const int t = t0 + c;
      int v = 255;
      if (qok && t < 1023) v = rowp[t];
      o |= ((unsigned)v & 255u) << (8*c);
    }
    *(unsigned*)(outp + t0) = o;
  }
}

// ---------------------------------------------------------------------------
// Merged Q/K/V projection. 768 blocks, 256 threads, 128x128 tile,
// DOUBLE-BUFFERED LDS, ONE barrier per K-step (R26-proven).
// sel=0: qh = (q Wq^T + bq)*scaleq   [B][H][S][D]
// sel=1: kh = (k Wk^T + bk)          [B][H][S][D]
// sel=2: vht2 = (v Wv^T + bv) tile-blocked [B][H][S/32][D][32]
// ---------------------------------------------------------------------------
__global__ __launch_bounds__(256)
void qkv_proj(const float* xq, const float* xk, const float* xv,
              const float* Wq, const float* Wk, const float* Wv,
              const float* bq, const float* bk, const float* bv,
              unsigned short* qh, unsigned short* kh, unsigned short* vht2,
              float scaleq)
{
  __shared__ unsigned short lda[2][128*40];   // 40-pad rows
  __shared__ unsigned short ldb[2][128*40];
  const int bid = blockIdx.x;
  const int sel = bid >> 8;                // uniform per block
  const int t   = bid & 255;
  const float *RA, *RB, *bias;
  int r0, c0;
  if (sel == 0){ RA = xq; RB = Wq; bias = bq; r0 = (t&63)*128; c0 = (t>>6)*128; }
  else if (sel == 1){ RA = xk; RB = Wk; bias = bk; r0 = (t&63)*128; c0 = (t>>6)*128; }
  else { RA = Wv; RB = xv; bias = bv; r0 = (t&3)*128; c0 = (t>>2)*128; }

  const int tid  = threadIdx.x;
  const int w    = tid>>6, lane = tid&63, lo = lane&31, hi = lane>>5;
  const int wr   = (w>>1)*64, wc = (w&1)*64;
  const int arow = tid>>1, kb = (tid&1)*16;

  f32x16 acc[2][2];
  #pragma unroll
  for (int i=0;i<2;i++)
    #pragma unroll
    for (int j=0;j<2;j++) acc[i][j] = zero16();

  float4 ra[4], rb4[4];

  // ---- prologue: load tile0; stage into buf0; load tile1; barrier ----
  {
    const float4* p = (const float4*)(RA + (r0+arow)*512 + kb);
    ra[0]=p[0]; ra[1]=p[1]; ra[2]=p[2]; ra[3]=p[3];
    const float4* pq = (const float4*)(RB + (c0+arow)*512 + kb);
    rb4[0]=pq[0]; rb4[1]=pq[1]; rb4[2]=pq[2]; rb4[3]=pq[3];
  }
  {
    uint4 w0, w1;
    w0.x = f2bf_pair(ra[0].x, ra[0].y); w0.y = f2bf_pair(ra[0].z, ra[0].w);
    w0.z = f2bf_pair(ra[1].x, ra[1].y); w0.w = f2bf_pair(ra[1].z, ra[1].w);
    w1.x = f2bf_pair(ra[2].x, ra[2].y); w1.y = f2bf_pair(ra[2].z, ra[2].w);
    w1.z = f2bf_pair(ra[3].x, ra[3].y); w1.w = f2bf_pair(ra[3].z, ra[3].w);
    uint4* pa = (uint4*)&lda[0][arow*40 + kb];
    pa[0] = w0; pa[1] = w1;
    uint4 v0, v1;
    v0.x = f2bf_pair(rb4[0].x, rb4[0].y); v0.y = f2bf_pair(rb4[0].z, rb4[0].w);
    v0.z = f2bf_pair(rb4[1].x, rb4[1].y); v0.w = f2bf_pair(rb4[1].z, rb4[1].w);
    v1.x = f2bf_pair(rb4[2].x, rb4[2].y); v1.y = f2bf_pair(rb4[2].z, rb4[2].w);
    v1.z = f2bf_pair(rb4[3].x, rb4[3].y); v1.w = f2bf_pair(rb4[3].z, rb4[3].w);
    uint4* pb = (uint4*)&ldb[0][arow*40 + kb];
    pb[0] = v0; pb[1] = v1;
  }
  {
    const float4* p = (const float4*)(RA + (r0+arow)*512 + 32 + kb);
    ra[0]=p[0]; ra[1]=p[1]; ra[2]=p[2]; ra[3]=p[3];
    const float4* pq = (const float4*)(RB + (c0+arow)*512 + 32 + kb);
    rb4[0]=pq[0]; rb4[1]=pq[1]; rb4[2]=pq[2]; rb4[3]=pq[3];
  }
  bar_lgkm();   // buf0 visible

  for (int ks=0; ks<16; ++ks){
    const int cur = ks & 1;
    // stage tile ks+1 into the OTHER buffer (regs loaded last iter)
    if (ks < 15){
      uint4 w0, w1;
      w0.x = f2bf_pair(ra[0].x, ra[0].y); w0.y = f2bf_pair(ra[0].z, ra[0].w);
      w0.z = f2bf_pair(ra[1].x, ra[1].y); w0.w = f2bf_pair(ra[1].z, ra[1].w);
      w1.x = f2bf_pair(ra[2].x, ra[2].y); w1.y = f2bf_pair(ra[2].z, ra[2].w);
      w1.z = f2bf_pair(ra[3].x, ra[3].y); w1.w = f2bf_pair(ra[3].z, ra[3].w);
      uint4* pa = (uint4*)&lda[cur^1][arow*40 + kb];
      pa[0] = w0; pa[1] = w1;
      uint4 v0, v1;
      v0.x = f2bf_pair(rb4[0].x, rb4[0].y); v0.y = f2bf_pair(rb4[0].z, rb4[0].w);
      v0.z = f2bf_pair(rb4[1].x, rb4[1].y); v0.w = f2bf_pair(rb4[1].z, rb4[1].w);
      v1.x = f2bf_pair(rb4[2].x, rb4[2].y); v1.y = f2bf_pair(rb4[2].z, rb4[2].w);
      v1.z = f2bf_pair(rb4[3].x, rb4[3].y); v1.w = f2bf_pair(rb4[3].z, rb4[3].w);
      uint4* pb = (uint4*)&ldb[cur^1][arow*40 + kb];
      pb[0] = v0; pb[1] = v1;
    }
    // issue loads for tile ks+2 (in flight across the barrier)
    if (ks < 14){
      const int k0 = (ks+2)*32;
      const float4* p = (const float4*)(RA + (r0+arow)*512 + k0 + kb);
      ra[0]=p[0]; ra[1]=p[1]; ra[2]=p[2]; ra[3]=p[3];
      const float4* pq = (const float4*)(RB + (c0+arow)*512 + k0 + kb);
      rb4[0]=pq[0]; rb4[1]=pq[1]; rb4[2]=pq[2]; rb4[3]=pq[3];
    }
    // MFMA from current buffer (visible via previous barrier)
    #pragma unroll
    for (int kf=0; kf<2; ++kf){
      bf16x8 af0 = *(const bf16x8*)&lda[cur][(wr+lo)*40    + kf*16 + hi*8];
      bf16x8 af1 = *(const bf16x8*)&lda[cur][(wr+32+lo)*40 + kf*16 + hi*8];
      bf16x8 bg0 = *(const bf16x8*)&ldb[cur][(wc+lo)*40    + kf*16 + hi*8];
      bf16x8 bg1 = *(const bf16x8*)&ldb[cur][(wc+32+lo)*40 + kf*16 + hi*8];
      acc[0][0] = __builtin_amdgcn_mfma_f32_32x32x16_bf16(af0, bg0, acc[0][0], 0,0,0);
      acc[0][1] = __builtin_amdgcn_mfma_f32_32x32x16_bf16(af0, bg1, acc[0][1], 0,0,0);
      acc[1][0] = __builtin_amdgcn_mfma_f32_32x32x16_bf16(af1, bg0, acc[1][0], 0,0,0);
      acc[1][1] = __builtin_amdgcn_mfma_f32_32x32x16_bf16(af1, bg1, acc[1][1], 0,0,0);
    }
    // ONE barrier: my reads of buf[cur] + writes of buf[cur^1] all drained
    bar_lgkm();
  }

  // epilogue; C/D layout: col = lane&31, row = (r&3)+8*(r>>2)+4*(lane>>5)
  #pragma unroll
  for (int mi=0;mi<2;mi++){
    #pragma unroll
    for (int ni=0;ni<2;ni++){
      #pragma unroll
      for (int r=0;r<16;r++){
        const int rl = wr + mi*32 + (r&3) + 8*(r>>2) + 4*hi;
        const int cl = wc + ni*32 + lo;
        const int rg = r0 + rl, cg = c0 + cl;
        float v = acc[mi][ni][r];
        if (sel == 0){
          v = (v + bias[cg]) * scaleq;
          const int bb = rg>>10, s = rg&1023, h = cg>>6, d = cg&63;
          qh[(((bb*8+h)*1024)+s)*64 + d] = f2bf(v);
        } else if (sel == 1){
          v = v + bias[cg];
          const int bb = rg>>10, s = rg&1023, h = cg>>6, d = cg&63;
          kh[(((bb*8+h)*1024)+s)*64 + d] = f2bf(v);
        } else {
          v = v + bias[rg];
          const int h = rg>>6, d = rg&63, bb = cg>>10, s = cg&1023;
          vht2[(((size_t)(bb*8+h)*32 + (s>>5))*64 + d)*32 + (s&31)] = f2bf(v);
        }
      }
    }
  }
}

// ---------------------------------------------------------------------------
// Out projection with fused partial-combine:
//   A[row][k] = (ctx0[row][k] + ctx1[row][k]) / (l0[b,h,s] + l1[b,h,s])
//   out[8192][512] = A Wo^T + bo (f32).
// ---------------------------------------------------------------------------
__global__ __launch_bounds__(256)
void out_proj(const unsigned short* ctx0, const unsigned short* ctx1,
              const float* lsump, const float* Wo, const float* bo, float* OUT)
{
  __shared__ unsigned short lda[128*40];
  __shared__ unsigned short ldb[128*40];
  const int tid  = threadIdx.x;
  const int r0   = blockIdx.x*128, c0 = blockIdx.y*128;
  const int w    = tid>>6, lane = tid&63, lo = lane&31, hi = lane>>5;
  const int wr   = (w>>1)*64, wc = (w&1)*64;
  const int arow = tid>>1, kb = (tid&1)*16;
  const int rgs  = r0 + arow, bb = rgs>>10, ss = rgs&1023;
  const float* lb0 = lsump + (size_t)(bb*8)*1024 + ss;        // ts=0, + h*1024
  const float* lb1 = lsump + (size_t)((8+bb)*8)*1024 + ss;    // ts=1

  f32x16 acc[2][2];
  #pragma unroll
  for (int i=0;i<2;i++)
    #pragma unroll
    for (int j=0;j<2;j++) acc[i][j] = zero16();

  uint4 ra0[2], ra1[2];
  float4 rb4[4];
  float l0, l1;

  {
    const uint4* p0 = (const uint4*)(ctx0 + rgs*512 + kb);
    ra0[0]=p0[0]; ra0[1]=p0[1];
    const uint4* p1 = (const uint4*)(ctx1 + rgs*512 + kb);
    ra1[0]=p1[0]; ra1[1]=p1[1];
    const int h = kb>>6;
    l0 = lb0[h*1024]; l1 = lb1[h*1024];
    const float4* pq = (const float4*)(Wo + (c0+arow)*512 + kb);
    rb4[0]=pq[0]; rb4[1]=pq[1]; rb4[2]=pq[2]; rb4[3]=pq[3];
  }

  for (int ks=0; ks<16; ++ks){
    bar_lgkm();
    {
      const float rn = __builtin_amdgcn_rcpf(l0 + l1);
      uint4 w0, w1;
      w0.x = comb2(ra0[0].x, ra1[0].x, rn); w0.y = comb2(ra0[0].y, ra1[0].y, rn);
      w0.z = comb2(ra0[0].z, ra1[0].z, rn); w0.w = comb2(ra0[0].w, ra1[0].w, rn);
      w1.x = comb2(ra0[1].x, ra1[1].x, rn); w1.y = comb2(ra0[1].y, ra1[1].y, rn);
      w1.z = comb2(ra0[1].z, ra1[1].z, rn); w1.w = comb2(ra0[1].w, ra1[1].w, rn);
      uint4* pa = (uint4*)&lda[arow*40 + kb];
      pa[0] = w0; pa[1] = w1;
      uint4 v0, v1;
      v0.x = f2bf_pair(rb4[0].x, rb4[0].y); v0.y = f2bf_pair(rb4[0].z, rb4[0].w);
      v0.z = f2bf_pair(rb4[1].x, rb4[1].y); v0.w = f2bf_pair(rb4[1].z, rb4[1].w);
      v1.x = f2bf_pair(rb4[2].x, rb4[2].y); v1.y = f2bf_pair(rb4[2].z, rb4[2].w);
      v1.z = f2bf_pair(rb4[3].x, rb4[3].y); v1.w = f2bf_pair(rb4[3].z, rb4[3].w);
      uint4* pb = (uint4*)&ldb[arow*40 + kb];
      pb[0] = v0; pb[1] = v1;
    }
    if (ks < 15){
      const int k0 = (ks+1)*32;
      const uint4* p0 = (const uint4*)(ctx0 + rgs*512 + k0 + kb);
      ra0[0]=p0[0]; ra0[1]=p0[1];
      const uint4* p1 = (const uint4*)(ctx1 + rgs*512 + k0 + kb);
      ra1[0]=p1[0]; ra1[1]=p1[1];
      const int h = (k0+kb)>>6;
      l0 = lb0[h*1024]; l1 = lb1[h*1024];
      const float4* pq = (const float4*)(Wo + (c0+arow)*512 + k0 + kb);
      rb4[0]=pq[0]; rb4[1]=pq[1]; rb4[2]=pq[2]; rb4[3]=pq[3];
    }
    bar_lgkm();
    #pragma unroll
    for (int kf=0; kf<2; ++kf){
      bf16x8 af0 = *(const bf16x8*)&lda[(wr+lo)*40    + kf*16 + hi*8];
      bf16x8 af1 = *(const bf16x8*)&lda[(wr+32+lo)*40 + kf*16 + hi*8];
      bf16x8 bg0 = *(const bf16x8*)&ldb[(wc+lo)*40    + kf*16 + hi*8];
      bf16x8 bg1 = *(const bf16x8*)&ldb[(wc+32+lo)*40 + kf*16 + hi*8];
      acc[0][0] = __builtin_amdgcn_mfma_f32_32x32x16_bf16(af0, bg0, acc[0][0], 0,0,0);
      acc[0][1] = __builtin_amdgcn_mfma_f32_32x32x16_bf16(af0, bg1, acc[0][1], 0,0,0);
      acc[1][0] = __builtin_amdgcn_mfma_f32_32x32x16_bf16(af1, bg0, acc[1][0], 0,0,0);
      acc[1][1] = __builtin_amdgcn_mfma_f32_32x32x16_bf16(af1, bg1, acc[1][1], 0,0,0);
    }
  }

  #pragma unroll
  for (int mi=0;mi<2;mi++){
    #pragma unroll
    for (int ni=0;ni<2;ni++){
      #pragma unroll
      for (int r=0;r<16;r++){
        const int rl = wr + mi*32 + (r&3) + 8*(r>>2) + 4*hi;
        const int cl = wc + ni*32 + lo;
        const int rg = r0 + rl, cg = c0 + cl;
        OUT[rg*512 + cg] = acc[mi][ni][r] + bo[cg];
      }
    }
  }
}

// ---------------------------------------------------------------------------
// Fused attention, LDS-STAGED + DOUBLE-BUFFERED (1 barrier/iter), u8 ab8.
// 1024 blocks x 256 thr = 4 waves; block = ONE head x FOUR q-tiles.
// XCD decode keyed on b: b = m&7. r = m>>3: h = r&7, ts = (r>>3)&1, sg = r>>4.
// kls stride 72 (ushort); vls stride 40 (ushort); abls [q 0..127][t' 0..31]
// u8 stride 36 (R34: q-major so the gather is 4 x ds_read_b32, not 16 x u8).
// tbl[0..254] = table*log2e, tbl[255] = vbias*log2e (boundary sentinel).
// ---------------------------------------------------------------------------
__global__ __launch_bounds__(256)
void attn_fused(const unsigned short* qh, const unsigned short* kh,
                const unsigned short* vht2, const unsigned char* ab8,
                const float* bias_table, const float* vbias,
                unsigned short* ctxp, float* lsump)
{
  __shared__ float tbl[256];                // [0..254]=table*log2e, 255=vbias
  __shared__ unsigned short kls[2][32*72];  // K tile [t'][d]
  __shared__ unsigned short vls[2][64*40];  // V tile [d][t']
  __shared__ unsigned char  abls[2][128*36];// ab tile [q 0..127][t' 0..31], u8

  const int tid = threadIdx.x;
  const int m   = blockIdx.x;
  const int b   = m & 7;                 // XCD key: all 128 blocks of b co-XCD
  const int r   = m >> 3;
  const int h   = r & 7;
  const int ts  = (r >> 3) & 1;
  const int sg  = r >> 4;                // q-group 0..7
  const int tb  = ts*512;
  const int q0  = sg*128;

  {
    const int i = tid;                   // 256 threads cover 256 entries
    float v = (i < 255) ? bias_table[i*8 + h] : vbias[h];
    tbl[i] = v * 1.4426950408889634f;
  }

  const int w = tid>>6, lane = tid&63, lo = lane&31, hi = lane>>5;
  const bool hib = (hi != 0);
  const int s0 = q0 + w*32;              // this wave's q-tile base

  const unsigned short* qbase  = qh   + (size_t)(b*8+h)*65536;
  const unsigned short* kbase  = kh   + (size_t)(b*8+h)*65536 + (size_t)tb*64;
  const unsigned short* vbase  = vht2 + ((size_t)(b*8+h)*32 + (tb>>5))*2048;
  const unsigned char*  abbase = ab8  + ((size_t)b<<20);   // [q][t]

  // Q fragments (B operand; Q[q = s0+lo][d-chunk]) — loaded once
  bf16x8 qf[4];
  #pragma unroll
  for (int kf=0; kf<4; ++kf)
    qf[kf] = *(const bf16x8*)&qbase[(s0+lo)*64 + kf*16 + hi*8];

  f32x16 accv[2]; accv[0] = zero16(); accv[1] = zero16();
  float lsum = 0.0f;

  // staging addresses (coalesced; 16B per thread per structure)
  const int kdst = (tid>>3)*72  + (tid&7)*8;    // K: row t'=tid/8, col d=(tid%8)*8
  const int vdst = (tid>>2)*40  + (tid&3)*8;    // V: row d=tid/4, col t'=(tid%4)*8
  const int adst = (tid>>1)*36  + (tid&1)*16;   // ab u8: row q'=tid/2, 16 t' each
  const size_t asrc = (size_t)(q0 + (tid>>1))*1024 + (tid&1)*16;  // + tb + tt

  // ---- prologue: load tile 0, stage into buf0, issue tile-1 loads, barrier ----
  uint4 krg, vrg, ar0;
  krg = *(const uint4*)&kbase[tid*8];
  vrg = *(const uint4*)&vbase[tid*8];
  ar0 = *(const uint4*)&abbase[asrc + tb];
  *(uint4*)&kls[0][kdst]  = krg;
  *(uint4*)&vls[0][vdst]  = vrg;
  *(uint4*)&abls[0][adst] = ar0;
  krg = *(const uint4*)&kbase[32*64 + tid*8];
  vrg = *(const uint4*)&vbase[2048 + tid*8];
  ar0 = *(const uint4*)&abbase[asrc + tb + 32];
  bar_lgkm();   // buf0 visible (also covers tbl)

  for (int tt=0; tt<512; tt+=32){
    const int cur = (tt>>5) & 1;
    // stage tile tt+32 into the OTHER buffer (vmcnt wait here, ~1 iter slack);
    // that buffer's iter-(tt-32) readers finished before the last barrier.
    *(uint4*)&kls[cur^1][kdst]  = krg;
    *(uint4*)&vls[cur^1][vdst]  = vrg;
    *(uint4*)&abls[cur^1][adst] = ar0;
    // issue loads for tile tt+64 (wrapped; extras on last iters harmless)
    {
      const int tn = (tt+64)&511;
      krg = *(const uint4*)&kbase[tn*64 + tid*8];
      vrg = *(const uint4*)&vbase[(tn>>5)*2048 + tid*8];
      ar0 = *(const uint4*)&abbase[asrc + tb + tn];
    }

    // QK^T swapped: sc[r] = S[t = tt + crow(r,hi)][q = s0+lo] (from buf[cur])
    f32x16 sc = zero16();
    #pragma unroll
    for (int kf=0; kf<4; ++kf){
      bf16x8 kfr = *(const bf16x8*)&kls[cur][lo*72 + kf*16 + hi*8];
      sc = __builtin_amdgcn_mfma_f32_32x32x16_bf16(kfr, qf[kf], sc, 0,0,0);
    }

    // bias gather: one u32 per g covers t' = 8g+4hi .. +3 (q-major tile)
    const unsigned char* abrow = &abls[cur][(w*32 + lo)*36];
    unsigned d[4][2];
    float ls = 0.0f;
    #pragma unroll
    for (int g=0; g<4; ++g){
      const unsigned v4 = *(const unsigned*)(abrow + 8*g + 4*hi);
      float p[4];
      #pragma unroll
      for (int u=0; u<4; ++u){
        const int idx = (v4 >> (8*u)) & 255;
        p[u] = __builtin_amdgcn_exp2f(sc[4*g+u] + tbl[idx]);
        ls  += p[u];
      }
      d[g][0] = f2bf_pair(p[0], p[1]);
      d[g][1] = f2bf_pair(p[2], p[3]);
    }
    lsum += ls;

    // exchange with partner lane (lo, 1-hi)
    unsigned x[4][2];
    #pragma unroll
    for (int g=0; g<4; ++g){
      x[g][0] = __shfl_xor(d[g][0], 32, 64);
      x[g][1] = __shfl_xor(d[g][1], 32, 64);
    }

    // PV: A-frag(c2) = hi ? {x[2c2+1], d[2c2+1]} : {d[2c2], x[2c2]}
    #pragma unroll
    for (int c2=0; c2<2; ++c2){
      union { unsigned u[4]; bf16x8 v; } pc;
      pc.u[0] = hib ? x[2*c2+1][0] : d[2*c2][0];
      pc.u[1] = hib ? x[2*c2+1][1] : d[2*c2][1];
      pc.u[2] = hib ? d[2*c2+1][0] : x[2*c2][0];
      pc.u[3] = hib ? d[2*c2+1][1] : x[2*c2][1];
      bf16x8 vf0 = *(const bf16x8*)&vls[cur][(     lo)*40 + c2*16 + hi*8];
      bf16x8 vf1 = *(const bf16x8*)&vls[cur][(32 + lo)*40 + c2*16 + hi*8];
      accv[0] = __builtin_amdgcn_mfma_f32_32x32x16_bf16(pc.v, vf0, accv[0], 0,0,0);
      accv[1] = __builtin_amdgcn_mfma_f32_32x32x16_bf16(pc.v, vf1, accv[1], 0,0,0);
    }
    // ONE barrier: my reads of buf[cur] + writes of buf[cur^1] all drained
    bar_lgkm();
  }

  // full partial row sum for q = s0+lo (combine the two hi-halves)
  lsum += __shfl_xor(lsum, 32, 64);

  // store UNNORMALIZED partial ctx bf16 (rows q = crow(r,hi), col d = lo)
  unsigned short* cbase = ctxp + (size_t)ts*4194304;   // 8*1024*512 per half
  #pragma unroll
  for (int dc=0; dc<2; ++dc){
    #pragma unroll
    for (int r2=0;r2<16;r2++){
      const int rq = (r2&3) + 8*(r2>>2) + 4*hi;
      cbase[((size_t)b*1024 + s0 + rq)*512 + h*64 + dc*32 + lo] = f2bf(accv[dc][r2]);
    }
  }
  if (hi == 0){
    lsump[((size_t)(ts*8 + b)*8 + h)*1024 + s0 + lo] = lsum;
  }
}

extern "C" void kernel_launch(void* const* d_in, const int* in_sizes, int n_in,
                              void* d_out, int out_size, void* d_ws, size_t ws_size,
                              hipStream_t stream)
{
  const float* q    = (const float*)d_in[0];
  const float* k    = (const float*)d_in[1];
  const float* v    = (const float*)d_in[2];
  const int*   ab   = (const int*)  d_in[3];
  const float* Wq   = (const float*)d_in[4];
  const float* bq   = (const float*)d_in[5];
  const float* Wk   = (const float*)d_in[6];
  const float* bk   = (const float*)d_in[7];
  const float* Wv   = (const float*)d_in[8];
  const float* bv   = (const float*)d_in[9];
  const float* Wo   = (const float*)d_in[10];
  const float* bo   = (const float*)d_in[11];
  const float* btab = (const float*)d_in[12];
  const float* vbia = (const float*)d_in[13];

  char* ws = (char*)d_ws;
  unsigned short* qh   = (unsigned short*)(ws);                    //  8 MB
  unsigned short* kh   = (unsigned short*)(ws + ((size_t) 8<<20)); //  8 MB
  unsigned short* vht2 = (unsigned short*)(ws + ((size_t)16<<20)); //  8 MB
  unsigned short* ctxp = (unsigned short*)(ws + ((size_t)24<<20)); // 16 MB (2 halves)
  float*          lsmp = (float*)         (ws + ((size_t)40<<20)); // 512 KB
  unsigned char*  ab8  = (unsigned char*) (ws + ((size_t)41<<20)); //  8 MB (u8)

  const float SCALE_Q = 0.125f * 1.4426950408889634f;  // D^-0.5 * log2(e)

  qkv_proj<<<768, 256, 0, stream>>>(q, k, v, Wq, Wk, Wv, bq, bk, bv,
                                    qh, kh, vht2, SCALE_Q);
  ab_u8<<<2048, 256, 0, stream>>>(ab, ab8);
  attn_fused<<<1024, 256, 0, stream>>>(qh, kh, vht2, ab8, btab, vbia,
                                       ctxp, lsmp);
  out_proj<<<dim3(64,4), 256, 0, stream>>>(ctxp, ctxp + (size_t)4194304,
                                           lsmp, Wo, bo, (float*)d_out);
}

// Round 35
// 115.508 us; speedup vs baseline: 1.2409x; 1.0486x over previous
//
#include <hip/hip_runtime.h>
#include <hip/hip_bf16.h>

// MultiHeadAttention fused pipeline, MI355X gfx950.
// B=8, S=1024 (N=1023 + 1 global), HID=512, H=8, D=64.
// Stages: qkv_proj (128x128 dbuf 1-barrier) -> qh/kh [B][H][S][D], vht2 blocked;
//         ab_u8 (streaming narrow, NO transpose) -> ab8 u8 [B][1024q][1024t];
//         attn_fused (LDS-staged, dbuf, b-keyed XCD, [q][t'] ab tile) -> partials;
//         out_proj 64x128 tiles (512 blocks = 2/CU) -> f32 out.
// Ladder: 194 -> 148 -> 128.2 -> 127.8 -> 125.9 -> 124.6 -> 121.3 -> 121.1 (R34).
// R35: out_proj was grid-starved: dim3(64,4)=256 blocks = 1 block/CU (the qkv
//   latency signature, but the limiter is purely grid size). Halve M-tile to
//   64x128 -> 512 blocks = 2/CU. Wave-tile 32x64 (af x {bg0,bg1}, 4 MFMA/wave/
//   step), A-staging 4 thr/row (1+1 uint4 + 4 comb2/thread/step, half prior),
//   B path identical, same 2-barrier loop. LDS 15KB. Floor ~8us.
//   Gate: total >= 121.5 or out_proj above qkv in top-5 => revert to R34.

typedef __attribute__((ext_vector_type(8)))  __bf16 bf16x8;
typedef __attribute__((ext_vector_type(16))) float  f32x16;

__device__ inline f32x16 zero16(){
  f32x16 z;
  #pragma unroll
  for (int i=0;i<16;i++) z[i] = 0.0f;
  return z;
}

__device__ inline unsigned short f2bf(float x){           // RNE f32->bf16
  unsigned u = __float_as_uint(x);
  u += 0x7fffu + ((u>>16)&1u);
  return (unsigned short)(u>>16);
}
__device__ inline unsigned f2bf_pair(float a, float b){   // pack 2 bf16 into dword (RNE)
  unsigned ua = __float_as_uint(a); ua += 0x7fffu + ((ua>>16)&1u);
  unsigned ub = __float_as_uint(b); ub += 0x7fffu + ((ub>>16)&1u);
  return (ua>>16) | (ub & 0xffff0000u);
}
// combine two packed-bf16 dwords: (a+b)*rn per element, repacked bf16
__device__ inline unsigned comb2(unsigned a, unsigned b, float rn){
  const float a0 = __uint_as_float(a<<16), a1 = __uint_as_float(a & 0xffff0000u);
  const float b0 = __uint_as_float(b<<16), b1 = __uint_as_float(b & 0xffff0000u);
  return f2bf_pair((a0+b0)*rn, (a1+b1)*rn);
}

__device__ inline void bar_lgkm(){   // LDS-visibility barrier WITHOUT vmcnt drain
  asm volatile("s_waitcnt lgkmcnt(0)" ::: "memory");
  __builtin_amdgcn_s_barrier();
}

// ---------------------------------------------------------------------------
// ab_u8: ab8[b][q][t] = (q<1023 && t<1023) ? (u8)ab[b][q][t] : 255.
// NO transpose, NO LDS: pure streaming narrow. 2048 blocks x 256 thr.
// ---------------------------------------------------------------------------
__global__ __launch_bounds__(256)
void ab_u8(const int* ab, unsigned char* ab8)
{
  const int k   = blockIdx.x;          // 2048 = 8 b x 256 row-groups
  const int b   = k >> 8;
  const int q   = ((k & 255) << 2) + (threadIdx.x >> 6);
  const int j   = threadIdx.x & 63;
  const bool qok = (q < 1023);
  const int* rowp = ab + ((size_t)b*1023 + q)*1023;
  unsigned char* outp = ab8 + ((size_t)b << 20) + (size_t)q*1024;
  #pragma unroll
  for (int i = 0; i < 4; ++i){
    const int t0 = (j + 64*i)*4;       // out byte base 0..1020
    unsigned o = 0;
    #pragma unroll
    for (int c = 0; c < 4; ++c){
      const int t = t0 + c;
      int v = 255;
      if (qok && t < 1023) v = rowp[t];
      o |= ((unsigned)v & 255u) << (8*c);
    }
    *(unsigned*)(outp + t0) = o;
  }
}

// ---------------------------------------------------------------------------
// Merged Q/K/V projection. 768 blocks, 256 threads, 128x128 tile,
// DOUBLE-BUFFERED LDS, ONE barrier per K-step (R26-proven).
// sel=0: qh = (q Wq^T + bq)*scaleq   [B][H][S][D]
// sel=1: kh = (k Wk^T + bk)          [B][H][S][D]
// sel=2: vht2 = (v Wv^T + bv) tile-blocked [B][H][S/32][D][32]
// ---------------------------------------------------------------------------
__global__ __launch_bounds__(256)
void qkv_proj(const float* xq, const float* xk, const float* xv,
              const float* Wq, const float* Wk, const float* Wv,
              const float* bq, const float* bk, const float* bv,
              unsigned short* qh, unsigned short* kh, unsigned short* vht2,
              float scaleq)
{
  __shared__ unsigned short lda[2][128*40];   // 40-pad rows
  __shared__ unsigned short ldb[2][128*40];
  const int bid = blockIdx.x;
  const int sel = bid >> 8;                // uniform per block
  const int t   = bid & 255;
  const float *RA, *RB, *bias;
  int r0, c0;
  if (sel == 0){ RA = xq; RB = Wq; bias = bq; r0 = (t&63)*128; c0 = (t>>6)*128; }
  else if (sel == 1){ RA = xk; RB = Wk; bias = bk; r0 = (t&63)*128; c0 = (t>>6)*128; }
  else { RA = Wv; RB = xv; bias = bv; r0 = (t&3)*128; c0 = (t>>2)*128; }

  const int tid  = threadIdx.x;
  const int w    = tid>>6, lane = tid&63, lo = lane&31, hi = lane>>5;
  const int wr   = (w>>1)*64, wc = (w&1)*64;
  const int arow = tid>>1, kb = (tid&1)*16;

  f32x16 acc[2][2];
  #pragma unroll
  for (int i=0;i<2;i++)
    #pragma unroll
    for (int j=0;j<2;j++) acc[i][j] = zero16();

  float4 ra[4], rb4[4];

  // ---- prologue: load tile0; stage into buf0; load tile1; barrier ----
  {
    const float4* p = (const float4*)(RA + (r0+arow)*512 + kb);
    ra[0]=p[0]; ra[1]=p[1]; ra[2]=p[2]; ra[3]=p[3];
    const float4* pq = (const float4*)(RB + (c0+arow)*512 + kb);
    rb4[0]=pq[0]; rb4[1]=pq[1]; rb4[2]=pq[2]; rb4[3]=pq[3];
  }
  {
    uint4 w0, w1;
    w0.x = f2bf_pair(ra[0].x, ra[0].y); w0.y = f2bf_pair(ra[0].z, ra[0].w);
    w0.z = f2bf_pair(ra[1].x, ra[1].y); w0.w = f2bf_pair(ra[1].z, ra[1].w);
    w1.x = f2bf_pair(ra[2].x, ra[2].y); w1.y = f2bf_pair(ra[2].z, ra[2].w);
    w1.z = f2bf_pair(ra[3].x, ra[3].y); w1.w = f2bf_pair(ra[3].z, ra[3].w);
    uint4* pa = (uint4*)&lda[0][arow*40 + kb];
    pa[0] = w0; pa[1] = w1;
    uint4 v0, v1;
    v0.x = f2bf_pair(rb4[0].x, rb4[0].y); v0.y = f2bf_pair(rb4[0].z, rb4[0].w);
    v0.z = f2bf_pair(rb4[1].x, rb4[1].y); v0.w = f2bf_pair(rb4[1].z, rb4[1].w);
    v1.x = f2bf_pair(rb4[2].x, rb4[2].y); v1.y = f2bf_pair(rb4[2].z, rb4[2].w);
    v1.z = f2bf_pair(rb4[3].x, rb4[3].y); v1.w = f2bf_pair(rb4[3].z, rb4[3].w);
    uint4* pb = (uint4*)&ldb[0][arow*40 + kb];
    pb[0] = v0; pb[1] = v1;
  }
  {
    const float4* p = (const float4*)(RA + (r0+arow)*512 + 32 + kb);
    ra[0]=p[0]; ra[1]=p[1]; ra[2]=p[2]; ra[3]=p[3];
    const float4* pq = (const float4*)(RB + (c0+arow)*512 + 32 + kb);
    rb4[0]=pq[0]; rb4[1]=pq[1]; rb4[2]=pq[2]; rb4[3]=pq[3];
  }
  bar_lgkm();   // buf0 visible

  for (int ks=0; ks<16; ++ks){
    const int cur = ks & 1;
    // stage tile ks+1 into the OTHER buffer (regs loaded last iter)
    if (ks < 15){
      uint4 w0, w1;
      w0.x = f2bf_pair(ra[0].x, ra[0].y); w0.y = f2bf_pair(ra[0].z, ra[0].w);
      w0.z = f2bf_pair(ra[1].x, ra[1].y); w0.w = f2bf_pair(ra[1].z, ra[1].w);
      w1.x = f2bf_pair(ra[2].x, ra[2].y); w1.y = f2bf_pair(ra[2].z, ra[2].w);
      w1.z = f2bf_pair(ra[3].x, ra[3].y); w1.w = f2bf_pair(ra[3].z, ra[3].w);
      uint4* pa = (uint4*)&lda[cur^1][arow*40 + kb];
      pa[0] = w0; pa[1] = w1;
      uint4 v0, v1;
      v0.x = f2bf_pair(rb4[0].x, rb4[0].y); v0.y = f2bf_pair(rb4[0].z, rb4[0].w);
      v0.z = f2bf_pair(rb4[1].x, rb4[1].y); v0.w = f2bf_pair(rb4[1].z, rb4[1].w);
      v1.x = f2bf_pair(rb4[2].x, rb4[2].y); v1.y = f2bf_pair(rb4[2].z, rb4[2].w);
      v1.z = f2bf_pair(rb4[3].x, rb4[3].y); v1.w = f2bf_pair(rb4[3].z, rb4[3].w);
      uint4* pb = (uint4*)&ldb[cur^1][arow*40 + kb];
      pb[0] = v0; pb[1] = v1;
    }
    // issue loads for tile ks+2 (in flight across the barrier)
    if (ks < 14){
      const int k0 = (ks+2)*32;
      const float4* p = (const float4*)(RA + (r0+arow)*512 + k0 + kb);
      ra[0]=p[0]; ra[1]=p[1]; ra[2]=p[2]; ra[3]=p[3];
      const float4* pq = (const float4*)(RB + (c0+arow)*512 + k0 + kb);
      rb4[0]=pq[0]; rb4[1]=pq[1]; rb4[2]=pq[2]; rb4[3]=pq[3];
    }
    // MFMA from current buffer (visible via previous barrier)
    #pragma unroll
    for (int kf=0; kf<2; ++kf){
      bf16x8 af0 = *(const bf16x8*)&lda[cur][(wr+lo)*40    + kf*16 + hi*8];
      bf16x8 af1 = *(const bf16x8*)&lda[cur][(wr+32+lo)*40 + kf*16 + hi*8];
      bf16x8 bg0 = *(const bf16x8*)&ldb[cur][(wc+lo)*40    + kf*16 + hi*8];
      bf16x8 bg1 = *(const bf16x8*)&ldb[cur][(wc+32+lo)*40 + kf*16 + hi*8];
      acc[0][0] = __builtin_amdgcn_mfma_f32_32x32x16_bf16(af0, bg0, acc[0][0], 0,0,0);
      acc[0][1] = __builtin_amdgcn_mfma_f32_32x32x16_bf16(af0, bg1, acc[0][1], 0,0,0);
      acc[1][0] = __builtin_amdgcn_mfma_f32_32x32x16_bf16(af1, bg0, acc[1][0], 0,0,0);
      acc[1][1] = __builtin_amdgcn_mfma_f32_32x32x16_bf16(af1, bg1, acc[1][1], 0,0,0);
    }
    // ONE barrier: my reads of buf[cur] + writes of buf[cur^1] all drained
    bar_lgkm();
  }

  // epilogue; C/D layout: col = lane&31, row = (r&3)+8*(r>>2)+4*(lane>>5)
  #pragma unroll
  for (int mi=0;mi<2;mi++){
    #pragma unroll
    for (int ni=0;ni<2;ni++){
      #pragma unroll
      for (int r=0;r<16;r++){
        const int rl = wr + mi*32 + (r&3) + 8*(r>>2) + 4*hi;
        const int cl = wc + ni*32 + lo;
        const int rg = r0 + rl, cg = c0 + cl;
        float v = acc[mi][ni][r];
        if (sel == 0){
          v = (v + bias[cg]) * scaleq;
          const int bb = rg>>10, s = rg&1023, h = cg>>6, d = cg&63;
          qh[(((bb*8+h)*1024)+s)*64 + d] = f2bf(v);
        } else if (sel == 1){
          v = v + bias[cg];
          const int bb = rg>>10, s = rg&1023, h = cg>>6, d = cg&63;
          kh[(((bb*8+h)*1024)+s)*64 + d] = f2bf(v);
        } else {
          v = v + bias[rg];
          const int h = rg>>6, d = rg&63, bb = cg>>10, s = cg&1023;
          vht2[(((size_t)(bb*8+h)*32 + (s>>5))*64 + d)*32 + (s&31)] = f2bf(v);
        }
      }
    }
  }
}

// ---------------------------------------------------------------------------
// Out projection, 64x128 tiles (R35): 512 blocks (dim3(128,4)) = 2 blocks/CU.
//   A[row][k] = (ctx0[row][k] + ctx1[row][k]) / (l0[b,h,s] + l1[b,h,s])
//   out[8192][512] = A Wo^T + bo (f32).
// Wave-tile 32x64: wr=(w>>1)*32, wc=(w&1)*64; af x {bg0,bg1} = 4 MFMA/wave/step.
// A-staging: 4 thr/row (arow2=tid>>2, kb2=(tid&3)*8 bf16) = 1+1 uint4 + 4 comb2.
// B-staging: identical to R34 (2 thr/row, 16 f32). Same 2-barrier loop.
// ---------------------------------------------------------------------------
__global__ __launch_bounds__(256)
void out_proj(const unsigned short* ctx0, const unsigned short* ctx1,
              const float* lsump, const float* Wo, const float* bo, float* OUT)
{
  __shared__ unsigned short lda[64*40];
  __shared__ unsigned short ldb[128*40];
  const int tid  = threadIdx.x;
  const int r0   = blockIdx.x*64, c0 = blockIdx.y*128;
  const int w    = tid>>6, lane = tid&63, lo = lane&31, hi = lane>>5;
  const int wr   = (w>>1)*32, wc = (w&1)*64;
  const int arow2 = tid>>2, kb2 = (tid&3)*8;    // A: 4 thr/row, 8 bf16 each
  const int brow  = tid>>1, kbb = (tid&1)*16;   // B: 2 thr/row, 16 f32 each
  const int rgs  = r0 + arow2, bb = rgs>>10, ss = rgs&1023;
  const float* lb0 = lsump + (size_t)(bb*8)*1024 + ss;        // ts=0, + h*1024
  const float* lb1 = lsump + (size_t)((8+bb)*8)*1024 + ss;    // ts=1

  f32x16 acc2[2];
  acc2[0] = zero16(); acc2[1] = zero16();

  uint4 ca0, ca1;
  float4 rb4[4];
  float l0, l1;

  {
    ca0 = *(const uint4*)(ctx0 + rgs*512 + kb2);
    ca1 = *(const uint4*)(ctx1 + rgs*512 + kb2);
    const int h = kb2>>6;                        // = 0
    l0 = lb0[h*1024]; l1 = lb1[h*1024];
    const float4* pq = (const float4*)(Wo + (c0+brow)*512 + kbb);
    rb4[0]=pq[0]; rb4[1]=pq[1]; rb4[2]=pq[2]; rb4[3]=pq[3];
  }

  for (int ks=0; ks<16; ++ks){
    bar_lgkm();
    {
      const float rn = __builtin_amdgcn_rcpf(l0 + l1);
      uint4 w0;
      w0.x = comb2(ca0.x, ca1.x, rn); w0.y = comb2(ca0.y, ca1.y, rn);
      w0.z = comb2(ca0.z, ca1.z, rn); w0.w = comb2(ca0.w, ca1.w, rn);
      *(uint4*)&lda[arow2*40 + kb2] = w0;
      uint4 v0, v1;
      v0.x = f2bf_pair(rb4[0].x, rb4[0].y); v0.y = f2bf_pair(rb4[0].z, rb4[0].w);
      v0.z = f2bf_pair(rb4[1].x, rb4[1].y); v0.w = f2bf_pair(rb4[1].z, rb4[1].w);
      v1.x = f2bf_pair(rb4[2].x, rb4[2].y); v1.y = f2bf_pair(rb4[2].z, rb4[2].w);
      v1.z = f2bf_pair(rb4[3].x, rb4[3].y); v1.w = f2bf_pair(rb4[3].z, rb4[3].w);
      uint4* pb = (uint4*)&ldb[brow*40 + kbb];
      pb[0] = v0; pb[1] = v1;
    }
    if (ks < 15){
      const int k0 = (ks+1)*32;
      ca0 = *(const uint4*)(ctx0 + rgs*512 + k0 + kb2);
      ca1 = *(const uint4*)(ctx1 + rgs*512 + k0 + kb2);
      const int h = (k0+kb2)>>6;
      l0 = lb0[h*1024]; l1 = lb1[h*1024];
      const float4* pq = (const float4*)(Wo + (c0+brow)*512 + k0 + kbb);
      rb4[0]=pq[0]; rb4[1]=pq[1]; rb4[2]=pq[2]; rb4[3]=pq[3];
    }
    bar_lgkm();
    #pragma unroll
    for (int kf=0; kf<2; ++kf){
      bf16x8 af  = *(const bf16x8*)&lda[(wr+lo)*40    + kf*16 + hi*8];
      bf16x8 bg0 = *(const bf16x8*)&ldb[(wc+lo)*40    + kf*16 + hi*8];
      bf16x8 bg1 = *(const bf16x8*)&ldb[(wc+32+lo)*40 + kf*16 + hi*8];
      acc2[0] = __builtin_amdgcn_mfma_f32_32x32x16_bf16(af, bg0, acc2[0], 0,0,0);
      acc2[1] = __builtin_amdgcn_mfma_f32_32x32x16_bf16(af, bg1, acc2[1], 0,0,0);
    }
  }

  #pragma unroll
  for (int ni=0;ni<2;ni++){
    #pragma unroll
    for (int r=0;r<16;r++){
      const int rl = wr + (r&3) + 8*(r>>2) + 4*hi;
      const int cl = wc + ni*32 + lo;
      const int rg = r0 + rl, cg = c0 + cl;
      OUT[rg*512 + cg] = acc2[ni][r] + bo[cg];
    }
  }
}

// ---------------------------------------------------------------------------
// Fused attention, LDS-STAGED + DOUBLE-BUFFERED (1 barrier/iter), u8 ab8.
// 1024 blocks x 256 thr = 4 waves; block = ONE head x FOUR q-tiles.
// XCD decode keyed on b: b = m&7. r = m>>3: h = r&7, ts = (r>>3)&1, sg = r>>4.
// kls stride 72 (ushort); vls stride 40 (ushort); abls [q 0..127][t' 0..31]
// u8 stride 36 (q-major so the gather is 4 x ds_read_b32, not 16 x u8).
// tbl[0..254] = table*log2e, tbl[255] = vbias*log2e (boundary sentinel).
// ---------------------------------------------------------------------------
__global__ __launch_bounds__(256)
void attn_fused(const unsigned short* qh, const unsigned short* kh,
                const unsigned short* vht2, const unsigned char* ab8,
                const float* bias_table, const float* vbias,
                unsigned short* ctxp, float* lsump)
{
  __shared__ float tbl[256];                // [0..254]=table*log2e, 255=vbias
  __shared__ unsigned short kls[2][32*72];  // K tile [t'][d]
  __shared__ unsigned short vls[2][64*40];  // V tile [d][t']
  __shared__ unsigned char  abls[2][128*36];// ab tile [q 0..127][t' 0..31], u8

  const int tid = threadIdx.x;
  const int m   = blockIdx.x;
  const int b   = m & 7;                 // XCD key: all 128 blocks of b co-XCD
  const int r   = m >> 3;
  const int h   = r & 7;
  const int ts  = (r >> 3) & 1;
  const int sg  = r >> 4;                // q-group 0..7
  const int tb  = ts*512;
  const int q0  = sg*128;

  {
    const int i = tid;                   // 256 threads cover 256 entries
    float v = (i < 255) ? bias_table[i*8 + h] : vbias[h];
    tbl[i] = v * 1.4426950408889634f;
  }

  const int w = tid>>6, lane = tid&63, lo = lane&31, hi = lane>>5;
  const bool hib = (hi != 0);
  const int s0 = q0 + w*32;              // this wave's q-tile base

  const unsigned short* qbase  = qh   + (size_t)(b*8+h)*65536;
  const unsigned short* kbase  = kh   + (size_t)(b*8+h)*65536 + (size_t)tb*64;
  const unsigned short* vbase  = vht2 + ((size_t)(b*8+h)*32 + (tb>>5))*2048;
  const unsigned char*  abbase = ab8  + ((size_t)b<<20);   // [q][t]

  // Q fragments (B operand; Q[q = s0+lo][d-chunk]) — loaded once
  bf16x8 qf[4];
  #pragma unroll
  for (int kf=0; kf<4; ++kf)
    qf[kf] = *(const bf16x8*)&qbase[(s0+lo)*64 + kf*16 + hi*8];

  f32x16 accv[2]; accv[0] = zero16(); accv[1] = zero16();
  float lsum = 0.0f;

  // staging addresses (coalesced; 16B per thread per structure)
  const int kdst = (tid>>3)*72  + (tid&7)*8;    // K: row t'=tid/8, col d=(tid%8)*8
  const int vdst = (tid>>2)*40  + (tid&3)*8;    // V: row d=tid/4, col t'=(tid%4)*8
  const int adst = (tid>>1)*36  + (tid&1)*16;   // ab u8: row q'=tid/2, 16 t' each
  const size_t asrc = (size_t)(q0 + (tid>>1))*1024 + (tid&1)*16;  // + tb + tt

  // ---- prologue: load tile 0, stage into buf0, issue tile-1 loads, barrier ----
  uint4 krg, vrg, ar0;
  krg = *(const uint4*)&kbase[tid*8];
  vrg = *(const uint4*)&vbase[tid*8];
  ar0 = *(const uint4*)&abbase[asrc + tb];
  *(uint4*)&kls[0][kdst]  = krg;
  *(uint4*)&vls[0][vdst]  = vrg;
  *(uint4*)&abls[0][adst] = ar0;
  krg = *(const uint4*)&kbase[32*64 + tid*8];
  vrg = *(const uint4*)&vbase[2048 + tid*8];
  ar0 = *(const uint4*)&abbase[asrc + tb + 32];
  bar_lgkm();   // buf0 visible (also covers tbl)

  for (int tt=0; tt<512; tt+=32){
    const int cur = (tt>>5) & 1;
    // stage tile tt+32 into the OTHER buffer (vmcnt wait here, ~1 iter slack);
    // that buffer's iter-(tt-32) readers finished before the last barrier.
    *(uint4*)&kls[cur^1][kdst]  = krg;
    *(uint4*)&vls[cur^1][vdst]  = vrg;
    *(uint4*)&abls[cur^1][adst] = ar0;
    // issue loads for tile tt+64 (wrapped; extras on last iters harmless)
    {
      const int tn = (tt+64)&511;
      krg = *(const uint4*)&kbase[tn*64 + tid*8];
      vrg = *(const uint4*)&vbase[(tn>>5)*2048 + tid*8];
      ar0 = *(const uint4*)&abbase[asrc + tb + tn];
    }

    // QK^T swapped: sc[r] = S[t = tt + crow(r,hi)][q = s0+lo] (from buf[cur])
    f32x16 sc = zero16();
    #pragma unroll
    for (int kf=0; kf<4; ++kf){
      bf16x8 kfr = *(const bf16x8*)&kls[cur][lo*72 + kf*16 + hi*8];
      sc = __builtin_amdgcn_mfma_f32_32x32x16_bf16(kfr, qf[kf], sc, 0,0,0);
    }

    // bias gather: one u32 per g covers t' = 8g+4hi .. +3 (q-major tile)
    const unsigned char* abrow = &abls[cur][(w*32 + lo)*36];
    unsigned d[4][2];
    float ls = 0.0f;
    #pragma unroll
    for (int g=0; g<4; ++g){
      const unsigned v4 = *(const unsigned*)(abrow + 8*g + 4*hi);
      float p[4];
      #pragma unroll
      for (int u=0; u<4; ++u){
        const int idx = (v4 >> (8*u)) & 255;
        p[u] = __builtin_amdgcn_exp2f(sc[4*g+u] + tbl[idx]);
        ls  += p[u];
      }
      d[g][0] = f2bf_pair(p[0], p[1]);
      d[g][1] = f2bf_pair(p[2], p[3]);
    }
    lsum += ls;

    // exchange with partner lane (lo, 1-hi)
    unsigned x[4][2];
    #pragma unroll
    for (int g=0; g<4; ++g){
      x[g][0] = __shfl_xor(d[g][0], 32, 64);
      x[g][1] = __shfl_xor(d[g][1], 32, 64);
    }

    // PV: A-frag(c2) = hi ? {x[2c2+1], d[2c2+1]} : {d[2c2], x[2c2]}
    #pragma unroll
    for (int c2=0; c2<2; ++c2){
      union { unsigned u[4]; bf16x8 v; } pc;
      pc.u[0] = hib ? x[2*c2+1][0] : d[2*c2][0];
      pc.u[1] = hib ? x[2*c2+1][1] : d[2*c2][1];
      pc.u[2] = hib ? d[2*c2+1][0] : x[2*c2][0];
      pc.u[3] = hib ? d[2*c2+1][1] : x[2*c2][1];
      bf16x8 vf0 = *(const bf16x8*)&vls[cur][(     lo)*40 + c2*16 + hi*8];
      bf16x8 vf1 = *(const bf16x8*)&vls[cur][(32 + lo)*40 + c2*16 + hi*8];
      accv[0] = __builtin_amdgcn_mfma_f32_32x32x16_bf16(pc.v, vf0, accv[0], 0,0,0);
      accv[1] = __builtin_amdgcn_mfma_f32_32x32x16_bf16(pc.v, vf1, accv[1], 0,0,0);
    }
    // ONE barrier: my reads of buf[cur] + writes of buf[cur^1] all drained
    bar_lgkm();
  }

  // full partial row sum for q = s0+lo (combine the two hi-halves)
  lsum += __shfl_xor(lsum, 32, 64);

  // store UNNORMALIZED partial ctx bf16 (rows q = crow(r,hi), col d = lo)
  unsigned short* cbase = ctxp + (size_t)ts*4194304;   // 8*1024*512 per half
  #pragma unroll
  for (int dc=0; dc<2; ++dc){
    #pragma unroll
    for (int r2=0;r2<16;r2++){
      const int rq = (r2&3) + 8*(r2>>2) + 4*hi;
      cbase[((size_t)b*1024 + s0 + rq)*512 + h*64 + dc*32 + lo] = f2bf(accv[dc][r2]);
    }
  }
  if (hi == 0){
    lsump[((size_t)(ts*8 + b)*8 + h)*1024 + s0 + lo] = lsum;
  }
}

extern "C" void kernel_launch(void* const* d_in, const int* in_sizes, int n_in,
                              void* d_out, int out_size, void* d_ws, size_t ws_size,
                              hipStream_t stream)
{
  const float* q    = (const float*)d_in[0];
  const float* k    = (const float*)d_in[1];
  const float* v    = (const float*)d_in[2];
  const int*   ab   = (const int*)  d_in[3];
  const float* Wq   = (const float*)d_in[4];
  const float* bq   = (const float*)d_in[5];
  const float* Wk   = (const float*)d_in[6];
  const float* bk   = (const float*)d_in[7];
  const float* Wv   = (const float*)d_in[8];
  const float* bv   = (const float*)d_in[9];
  const float* Wo   = (const float*)d_in[10];
  const float* bo   = (const float*)d_in[11];
  const float* btab = (const float*)d_in[12];
  const float* vbia = (const float*)d_in[13];

  char* ws = (char*)d_ws;
  unsigned short* qh   = (unsigned short*)(ws);                    //  8 MB
  unsigned short* kh   = (unsigned short*)(ws + ((size_t) 8<<20)); //  8 MB
  unsigned short* vht2 = (unsigned short*)(ws + ((size_t)16<<20)); //  8 MB
  unsigned short* ctxp = (unsigned short*)(ws + ((size_t)24<<20)); // 16 MB (2 halves)
  float*          lsmp = (float*)         (ws + ((size_t)40<<20)); // 512 KB
  unsigned char*  ab8  = (unsigned char*) (ws + ((size_t)41<<20)); //  8 MB (u8)

  const float SCALE_Q = 0.125f * 1.4426950408889634f;  // D^-0.5 * log2(e)

  qkv_proj<<<768, 256, 0, stream>>>(q, k, v, Wq, Wk, Wv, bq, bk, bv,
                                    qh, kh, vht2, SCALE_Q);
  ab_u8<<<2048, 256, 0, stream>>>(ab, ab8);
  attn_fused<<<1024, 256, 0, stream>>>(qh, kh, vht2, ab8, btab, vbia,
                                       ctxp, lsmp);
  out_proj<<<dim3(128,4), 256, 0, stream>>>(ctxp, ctxp + (size_t)4194304,
                                            lsmp, Wo, bo, (float*)d_out);
}